// Round 7
// baseline (613.413 us; speedup 1.0000x reference)
//
#include <hip/hip_runtime.h>

// ---------------------------------------------------------------------------
// Types / helpers
// ---------------------------------------------------------------------------
typedef short s16x8 __attribute__((ext_vector_type(8)));
typedef short s16x4 __attribute__((ext_vector_type(4)));
typedef float f32x4 __attribute__((ext_vector_type(4)));
typedef __bf16 bf16x8 __attribute__((ext_vector_type(8)));

__device__ __forceinline__ float bf2f(short u) {
  union { unsigned int i; float f; } c;
  c.i = ((unsigned int)(unsigned short)u) << 16;
  return c.f;
}
__device__ __forceinline__ short f2bf(float f) {
  union { float f; unsigned int i; } c; c.f = f;
  unsigned int r = c.i + 0x7FFFu + ((c.i >> 16) & 1u);  // RNE
  return (short)(r >> 16);
}
__device__ __forceinline__ float sigmoidf_(float x) { return 1.f / (1.f + __expf(-x)); }

template <typename T>
__device__ __forceinline__ auto mfma_sel(T a, T b, f32x4 c, int)
    -> decltype(__builtin_amdgcn_mfma_f32_16x16x32_bf16(a, b, c, 0, 0, 0)) {
  return __builtin_amdgcn_mfma_f32_16x16x32_bf16(a, b, c, 0, 0, 0);
}
template <typename T>
__device__ __forceinline__ f32x4 mfma_sel(T a, T b, f32x4 c, long) {
  return __builtin_amdgcn_mfma_f32_16x16x32_bf16(
      __builtin_bit_cast(bf16x8, a), __builtin_bit_cast(bf16x8, b), c, 0, 0, 0);
}
__device__ __forceinline__ f32x4 MFMA16(s16x8 a, s16x8 b, f32x4 c) {
  return mfma_sel(a, b, c, 0);
}

__device__ __forceinline__ void gl2lds16(const void* g, void* l) {
  __builtin_amdgcn_global_load_lds(
      (const __attribute__((address_space(1))) unsigned int*)g,
      (__attribute__((address_space(3))) unsigned int*)l, 16, 0, 0);
}

// Counted-vmcnt pipeline (T4). Per K-tile each thread issues 4 loads in 2
// units of 2. At a tile boundary: outstanding = 4 (current tile) + 2 (next
// tile's unitA, issued just before the wait) -> vmcnt(2) == current tile
// fully landed, next tile's first unit stays in flight.
#define WAIT_VM2()  asm volatile("s_waitcnt vmcnt(2)" ::: "memory")
#define WAIT_VM0()  asm volatile("s_waitcnt vmcnt(0)" ::: "memory")
#define BAR()       __builtin_amdgcn_s_barrier()
#define PRIO1()     __builtin_amdgcn_s_setprio(1)
#define PRIO0()     __builtin_amdgcn_s_setprio(0)

// Bijective XCD-chunked swizzle (m204).
__device__ __forceinline__ int xcd_swz(int id, int nwg) {
  int q = nwg >> 3, r = nwg & 7;
  int xcd = id & 7, idx = id >> 3;
  return (xcd < r ? xcd * (q + 1) : r * (q + 1) + (xcd - r) * q) + idx;
}

// Superblocks of 8 m-rows, m fastest (B-panel L2-hot). gridDim.y == 64.
__device__ __forceinline__ void tile_mn(int nid, int gx, int* mt, int* nt) {
  int sb = nid / (gx << 3);
  int rem = nid - sb * (gx << 3);
  *mt = (sb << 3) + (rem & 7);
  *nt = rem >> 3;
}

// ---------------------------------------------------------------------------
// Workspace layout (byte offsets)
// ---------------------------------------------------------------------------
#define OFF_WADA1    0u
#define OFF_WQKVG    2359296u
#define OFF_WO       7077888u
#define OFF_WGATES   8257536u
#define OFF_WTMPQKV  10616832u
#define OFF_WTMPO    14155776u
#define OFF_WADA2    15335424u
#define OFF_WTRANS   17694720u
#define OFF_WBA      22413312u
#define OFF_BIAS     24772608u
#define OFF_ZT       24812544u
#define OFF_AN1      31104000u
#define OFF_SN1      43686912u
#define OFF_SN2      56269824u
#define OFF_SBF      68852736u
#define OFF_CADA     81435648u
#define OFF_QKVG     106601472u
#define OFF_GATES    156933120u
#define OFF_OGO      182098944u
#define OFF_A1       194681856u

// ---------------------------------------------------------------------------
// Mega prep kernel (unchanged)
// ---------------------------------------------------------------------------
__global__ __launch_bounds__(256) void prep_all(
    const float* p0, const float* p1, const float* p2, const float* p3,
    const float* p4, const float* p5, const float* p6, const float* p7,
    const float* p8, const float* p9, const float* p10, const float* p11,
    const float* p12, const float* p13, const float* p14, const float* p15,
    const float* p16, const float* p17, short* wsb,
    const float* __restrict__ zsrc, const float* __restrict__ ada_scale_b,
    const float* __restrict__ pb_q_b, const float* __restrict__ op_b,
    const float* __restrict__ tr_out_b, const float* __restrict__ tmp_q_b,
    const float* __restrict__ tr_scale_b,
    float* __restrict__ biasbuf, short* __restrict__ zt,
    const float* __restrict__ a_in, const float* __restrict__ s_in,
    const float* __restrict__ lnw1, const float* __restrict__ lnw2,
    short* __restrict__ an1, short* __restrict__ sn1, short* __restrict__ sn2,
    short* __restrict__ sbf) {
  const int z = blockIdx.z;
  const int tid = threadIdx.y * 32 + threadIdx.x;
  if (z < 18) {
    struct E { int K, N, dst; };
    const E tab[18] = {
        {768, 768, 0},        {768, 768, 589824},
        {768, 768, 1179648},  {768, 768, 1769472},
        {768, 768, 2359296},  {768, 768, 2949120},
        {768, 768, 3538944},
        {768, 768, 4128768},  {768, 768, 4718592},
        {768, 768, 7667712},  {768, 768, 8257536},
        {768, 1536, 8847360}, {768, 1536, 10027008},
        {1536, 768, 11206656},
        {768, 768, 5308416},  {768, 768, 5898240}, {768, 768, 6488064},
        {768, 768, 7077888}};
    int K = tab[z].K, N = tab[z].N;
    int n0 = blockIdx.x << 5, k0 = blockIdx.y << 5;
    if (n0 >= N || k0 >= K) return;
    const float* src;
    switch (z) {
      case 0: src = p0; break;  case 1: src = p1; break;
      case 2: src = p2; break;  case 3: src = p3; break;
      case 4: src = p4; break;  case 5: src = p5; break;
      case 6: src = p6; break;  case 7: src = p7; break;
      case 8: src = p8; break;  case 9: src = p9; break;
      case 10: src = p10; break; case 11: src = p11; break;
      case 12: src = p12; break; case 13: src = p13; break;
      case 14: src = p14; break; case 15: src = p15; break;
      case 16: src = p16; break; default: src = p17; break;
    }
    short* dst = wsb + tab[z].dst;
    __shared__ float tile[32][33];
    int tx = threadIdx.x, ty = threadIdx.y;
#pragma unroll
    for (int j = 0; j < 4; j++)
      tile[ty + j * 8][tx] = src[(long)(k0 + ty + j * 8) * N + n0 + tx];
    __syncthreads();
#pragma unroll
    for (int j = 0; j < 4; j++)
      dst[(long)(n0 + ty + j * 8) * K + k0 + tx] = f2bf(tile[tx][ty + j * 8]);
  } else if (z == 18) {
    const int bid = blockIdx.y * 48 + blockIdx.x;
    if (bid < 512) {
      const int b = bid >> 8, qq = bid & 255;
      const float* src = zsrc + (long)bid * 3072 + tid * 12;
      f32x4 v0 = *(const f32x4*)(src);
      f32x4 v1 = *(const f32x4*)(src + 4);
      f32x4 v2 = *(const f32x4*)(src + 8);
      float vals[12] = {v0[0], v0[1], v0[2], v0[3], v1[0], v1[1],
                        v1[2], v1[3], v2[0], v2[1], v2[2], v2[3]};
#pragma unroll
      for (int h = 0; h < 12; h++)
        zt[(((long)(b * 12 + h) * 256 + qq) << 8) + tid] = f2bf(vals[h]);
    } else if (bid < 551) {
      int j = (bid - 512) * 256 + tid;
      if (j < 9984) {
        float v;
        if (j < 1536) v = (j < 768) ? ada_scale_b[j] : 0.f;
        else if (j < 4608) { int jj = j - 1536; v = (jj < 768) ? pb_q_b[jj] : 0.f; }
        else if (j < 6144) { int jj = j - 4608; v = (jj < 768) ? op_b[jj] : tr_out_b[jj - 768]; }
        else if (j < 8448) { int jj = j - 6144; v = (jj < 768) ? tmp_q_b[jj] : 0.f; }
        else { int jj = j - 8448; v = (jj < 768) ? tr_scale_b[jj] : 0.f; }
        biasbuf[j] = v;
      }
    }
  } else {
    const int bid = blockIdx.y * 48 + blockIdx.x;
    if (bid >= 2048) return;
    const int wave = tid >> 6, lane = tid & 63;
    const int row = (bid << 2) + wave;
    const float* ar = a_in + (long)row * 768;
    const float* sr = s_in + (long)row * 768;
    f32x4 av[3], sv[3];
    float s0 = 0, s1 = 0, s2 = 0, s3 = 0;
#pragma unroll
    for (int k = 0; k < 3; k++) {
      int col = (lane << 2) + (k << 8);
      av[k] = *(const f32x4*)(ar + col);
      sv[k] = *(const f32x4*)(sr + col);
#pragma unroll
      for (int e = 0; e < 4; e++) {
        s0 += av[k][e]; s1 += av[k][e] * av[k][e];
        s2 += sv[k][e]; s3 += sv[k][e] * sv[k][e];
      }
    }
#pragma unroll
    for (int o = 32; o; o >>= 1) {
      s0 += __shfl_xor(s0, o, 64); s1 += __shfl_xor(s1, o, 64);
      s2 += __shfl_xor(s2, o, 64); s3 += __shfl_xor(s3, o, 64);
    }
    const float inv768 = 1.f / 768.f;
    float ma = s0 * inv768, va = s1 * inv768 - ma * ma;
    float ia = rsqrtf(va + 1e-5f);
    float ms = s2 * inv768, vs = s3 * inv768 - ms * ms;
    float is_ = rsqrtf(vs + 1e-5f);
#pragma unroll
    for (int k = 0; k < 3; k++) {
      int col = (lane << 2) + (k << 8);
      long o = (long)row * 768 + col;
      s16x4 o1, o2, o3, o4;
#pragma unroll
      for (int e = 0; e < 4; e++) {
        o1[e] = f2bf((av[k][e] - ma) * ia);
        float sn = (sv[k][e] - ms) * is_;
        o2[e] = f2bf(sn * lnw1[col + e]);
        o3[e] = f2bf(sn * lnw2[col + e]);
        o4[e] = f2bf(sv[k][e]);
      }
      *(s16x4*)(an1 + o) = o1;
      *(s16x4*)(sn1 + o) = o2;
      *(s16x4*)(sn2 + o) = o3;
      *(s16x4*)(sbf + o) = o4;
    }
  }
}

// ---------------------------------------------------------------------------
// ln_affine (unchanged)
// ---------------------------------------------------------------------------
__global__ __launch_bounds__(256) void ln_affine(
    const float* __restrict__ in, const float* __restrict__ w,
    const float* __restrict__ b, short* __restrict__ out) {
  const int wave = threadIdx.x >> 6, lane = threadIdx.x & 63;
  const int row = (blockIdx.x << 2) + wave;
  const float* xr = in + (long)row * 768;
  f32x4 xv[3];
  float s0 = 0, s1 = 0;
#pragma unroll
  for (int k = 0; k < 3; k++) {
    int col = (lane << 2) + (k << 8);
    xv[k] = *(const f32x4*)(xr + col);
#pragma unroll
    for (int e = 0; e < 4; e++) { s0 += xv[k][e]; s1 += xv[k][e] * xv[k][e]; }
  }
#pragma unroll
  for (int o = 32; o; o >>= 1) { s0 += __shfl_xor(s0, o, 64); s1 += __shfl_xor(s1, o, 64); }
  const float inv768 = 1.f / 768.f;
  float m = s0 * inv768, v = s1 * inv768 - m * m;
  float inv = rsqrtf(v + 1e-5f);
#pragma unroll
  for (int k = 0; k < 3; k++) {
    int col = (lane << 2) + (k << 8);
    s16x4 p;
#pragma unroll
    for (int e = 0; e < 4; e++) {
      float y = (xv[k][e] - m) * inv;
      if (w) y = y * w[col + e] + b[col + e];
      p[e] = f2bf(y);
    }
    *(s16x4*)(out + (long)row * 768 + col) = p;
  }
}

// ---------------------------------------------------------------------------
// GEMM engine v3 — 128(m)x128(n) tile, 512 threads (8 waves, 2m x 4n),
// 64 KB double-buffered LDS (proven envelope), phase-split pipeline:
//   per K-tile: 2 staging units {A,B} of 2 loads/thread; 4 phases, phase p
//   computes m-quarter p (4 MFMA); unitB of tile t+1 issued between phases.
//   Boundary: issue unitA(t+1); vmcnt(2) [tile t landed, unitA(t+1) in
//   flight]; raw BAR (RAW guard); ... ; end-of-tile BAR (WAR guard).
// Wave tile 64m x 32n -> acc[4][2]. setprio(1) around MFMA (T5).
// 2 blocks/CU -> 16 waves/CU (4/SIMD) — 2x r5's latency-hiding TLP.
// EP: 0 bf16(+bias), 1 bf16 sigmoid(+bias), 2 f32 res+acc, 3 f32 res+gate*acc
// ---------------------------------------------------------------------------
template <int EP>
__device__ __forceinline__ void dev_gemm_bt(
    short* lds,
    const short* __restrict__ A, const short* __restrict__ W,
    const float* __restrict__ bias, void* __restrict__ Cout,
    const float* __restrict__ res, const short* __restrict__ gate,
    int K, int ldA, int ldC, int gld) {
  const int tid = threadIdx.x;           // 0..511
  const int wave = tid >> 6;             // 0..7
  const int lane = tid & 63;
  const int gx = gridDim.x;
  const int nid = xcd_swz(blockIdx.y * gx + blockIdx.x, gx * gridDim.y);
  int mt_, nt_;
  tile_mn(nid, gx, &mt_, &nt_);
  const int m0 = mt_ << 7;
  const int n0 = nt_ << 7;
  const int wm = (wave & 1) << 6;        // 0,64
  const int wn = (wave >> 1) << 5;       // 0,32,64,96
  const int q = lane >> 4, r = lane & 15;
  f32x4 acc[4][2];
#pragma unroll
  for (int i = 0; i < 4; i++)
#pragma unroll
    for (int j = 0; j < 2; j++) acc[i][j] = (f32x4){0.f, 0.f, 0.f, 0.f};

  // Staging: 1024 chunks of 8 shorts per operand; thread covers chunks
  // c = j*512 + tid (j=0,1). Row = c>>3, swizzled k-chunk kc=(c&7)^(row&7).
  const short* pA[2];
  const short* pB[2];
#pragma unroll
  for (int j = 0; j < 2; j++) {
    int c = (j << 9) + tid;
    int m = c >> 3, kc = (c & 7) ^ (m & 7);
    pA[j] = A + (long)(m0 + m) * ldA + (kc << 3);
    pB[j] = W + (long)(n0 + m) * K + (kc << 3);
  }
  // Wave-uniform LDS bases (shorts): chunk*8 = j*4096 + wave*512 (+lane*8 HW).
  const int lA0 = (wave << 9);
  const int lA1 = (1 << 12) + (wave << 9);
  const int lB0 = 8192 + (wave << 9);
  const int lB1 = 8192 + (1 << 12) + (wave << 9);

  // ds_read short-offsets.
  int offA[4][2], offB[2][2];
#pragma unroll
  for (int p = 0; p < 4; p++)
#pragma unroll
    for (int ks = 0; ks < 2; ks++) {
      int row = wm + (p << 4) + r;
      offA[p][ks] = ((row << 3) + (((ks << 2) + q) ^ (row & 7))) << 3;
    }
#pragma unroll
  for (int ks = 0; ks < 2; ks++)
#pragma unroll
    for (int nt = 0; nt < 2; nt++) {
      int row = wn + (nt << 4) + r;
      offB[ks][nt] = 8192 + (((row << 3) + (((ks << 2) + q) ^ (row & 7))) << 3);
    }

  auto unitA = [&](short* buf, int ko) {
    gl2lds16(pA[0] + ko, buf + lA0);
    gl2lds16(pA[1] + ko, buf + lA1);
  };
  auto unitB = [&](short* buf, int ko) {
    gl2lds16(pB[0] + ko, buf + lB0);
    gl2lds16(pB[1] + ko, buf + lB1);
  };

  s16x8 bv[2][2];
  auto loadbv = [&](const short* buf) {
#pragma unroll
    for (int ks = 0; ks < 2; ks++)
#pragma unroll
      for (int nt = 0; nt < 2; nt++)
        bv[ks][nt] = *(const s16x8*)(buf + offB[ks][nt]);
  };
  auto phase = [&](const short* buf, int p) {
    s16x8 a0 = *(const s16x8*)(buf + offA[p][0]);
    s16x8 a1 = *(const s16x8*)(buf + offA[p][1]);
    PRIO1();
#pragma unroll
    for (int nt = 0; nt < 2; nt++) {
      acc[p][nt] = MFMA16(bv[0][nt], a0, acc[p][nt]);
      acc[p][nt] = MFMA16(bv[1][nt], a1, acc[p][nt]);
    }
    PRIO0();
  };

  // TILE: compute tile in cur; stage next tile (k-offset ko) into nxt.
  auto TILE = [&](const short* cur, short* nxt, int ko) {
    unitA(nxt, ko);
    WAIT_VM2(); BAR();
    loadbv(cur);
    phase(cur, 0);
    unitB(nxt, ko);
    phase(cur, 1);
    phase(cur, 2);
    phase(cur, 3);
    BAR();
  };

  short* b0 = lds;
  short* b1 = lds + 16384;
  const int NT = K >> 6;  // even (12 or 24)
  unitA(b0, 0); unitB(b0, 0);
  int t = 0;
  for (; t + 2 < NT; t += 2) {
    TILE(b0, b1, (t + 1) << 6);
    TILE(b1, b0, (t + 2) << 6);
  }
  TILE(b0, b1, (t + 1) << 6);  // computes tile NT-2, stages NT-1
  WAIT_VM0(); BAR();
  loadbv(b1);
  phase(b1, 0); phase(b1, 1); phase(b1, 2); phase(b1, 3);

#pragma unroll
  for (int mt = 0; mt < 4; mt++) {
    const int gm = m0 + wm + (mt << 4) + r;
#pragma unroll
    for (int nt = 0; nt < 2; nt++) {
      const int gnb = n0 + wn + (nt << 4) + (q << 2);
      f32x4 v = acc[mt][nt];
      if (bias) {
        f32x4 b4 = *(const f32x4*)(bias + gnb);
        v += b4;
      }
      long o = (long)gm * ldC + gnb;
      if (EP == 0) {
        s16x4 p;
#pragma unroll
        for (int e = 0; e < 4; e++) p[e] = f2bf(v[e]);
        *(s16x4*)((short*)Cout + o) = p;
      } else if (EP == 1) {
        s16x4 p;
#pragma unroll
        for (int e = 0; e < 4; e++) p[e] = f2bf(sigmoidf_(v[e]));
        *(s16x4*)((short*)Cout + o) = p;
      } else if (EP == 2) {
        f32x4 r4 = *(const f32x4*)(res + o);
        *(f32x4*)((float*)Cout + o) = r4 + v;
      } else {
        f32x4 r4 = *(const f32x4*)(res + o);
        s16x4 g4 = *(const s16x4*)(gate + (long)gm * gld + gnb);
        f32x4 out;
#pragma unroll
        for (int e = 0; e < 4; e++) out[e] = r4[e] + bf2f(g4[e]) * v[e];
        *(f32x4*)((float*)Cout + o) = out;
      }
    }
  }
}

// Dual GEMM v3 — 128(m) x (64|64)(n) halves, 512 threads (8 waves, 2m x 4n),
// same pipeline; units {A(2), B1+B2(2)}. Wave tile 64m x 16n per half ->
// acc1[4][1], acc2[4][1]. LDS: A 16KB + B1 8KB + B2 8KB = 32KB/buffer.
// MODE 0 (adaln): out = bf16( sigmoid(c1+bias)*an + c2 ); MODE 1: silu(c1)*c2
template <int MODE>
__device__ __forceinline__ void dev_gemm_dual(
    short* lds,
    const short* __restrict__ A, const short* __restrict__ W, int woff2,
    const float* __restrict__ bias, const short* __restrict__ an,
    short* __restrict__ out, int ldO) {
  const int tid = threadIdx.x;
  const int wave = tid >> 6, lane = tid & 63;
  const int gx = gridDim.x;
  const int nid = xcd_swz(blockIdx.y * gx + blockIdx.x, gx * gridDim.y);
  int mt_, nt_;
  tile_mn(nid, gx, &mt_, &nt_);
  const int m0 = mt_ << 7;
  const int n0 = nt_ << 6;               // 64-col tiles per half
  const int wm = (wave & 1) << 6;        // 0,64
  const int wn = (wave >> 1) << 4;       // 0,16,32,48
  const int q = lane >> 4, r = lane & 15;
  f32x4 acc1[4], acc2[4];
#pragma unroll
  for (int i = 0; i < 4; i++) {
    acc1[i] = (f32x4){0.f, 0.f, 0.f, 0.f};
    acc2[i] = (f32x4){0.f, 0.f, 0.f, 0.f};
  }

  const short* pA[2];
  const short* pB1;
  const short* pB2;
#pragma unroll
  for (int j = 0; j < 2; j++) {
    int c = (j << 9) + tid;
    int m = c >> 3, kc = (c & 7) ^ (m & 7);
    pA[j] = A + (long)(m0 + m) * 768 + (kc << 3);
  }
  {
    int m = tid >> 3, kc = (tid & 7) ^ (m & 7);
    pB1 = W + (long)(n0 + m) * 768 + (kc << 3);
    pB2 = W + (long)(woff2 + n0 + m) * 768 + (kc << 3);
  }
  const int lA0 = (wave << 9);
  const int lA1 = (1 << 12) + (wave << 9);
  const int lB1o = 8192 + (wave << 9);
  const int lB2o = 12288 + (wave << 9);

  int offA[4][2], offB[2];
#pragma unroll
  for (int p = 0; p < 4; p++)
#pragma unroll
    for (int ks = 0; ks < 2; ks++) {
      int row = wm + (p << 4) + r;
      offA[p][ks] = ((row << 3) + (((ks << 2) + q) ^ (row & 7))) << 3;
    }
#pragma unroll
  for (int ks = 0; ks < 2; ks++) {
    int row = wn + r;
    offB[ks] = ((row << 3) + (((ks << 2) + q) ^ (row & 7))) << 3;
  }

  auto unitA = [&](short* buf, int ko) {
    gl2lds16(pA[0] + ko, buf + lA0);
    gl2lds16(pA[1] + ko, buf + lA1);
  };
  auto unitB = [&](short* buf, int ko) {
    gl2lds16(pB1 + ko, buf + lB1o);
    gl2lds16(pB2 + ko, buf + lB2o);
  };

  s16x8 b1v[2], b2v[2];
  auto loadbv = [&](const short* buf) {
#pragma unroll
    for (int ks = 0; ks < 2; ks++) {
      b1v[ks] = *(const s16x8*)(buf + 8192 + offB[ks]);
      b2v[ks] = *(const s16x8*)(buf + 12288 + offB[ks]);
    }
  };
  auto phase = [&](const short* buf, int p) {
    s16x8 a0 = *(const s16x8*)(buf + offA[p][0]);
    s16x8 a1 = *(const s16x8*)(buf + offA[p][1]);
    PRIO1();
    acc1[p] = MFMA16(b1v[0], a0, acc1[p]);
    acc1[p] = MFMA16(b1v[1], a1, acc1[p]);
    acc2[p] = MFMA16(b2v[0], a0, acc2[p]);
    acc2[p] = MFMA16(b2v[1], a1, acc2[p]);
    PRIO0();
  };
  auto TILE = [&](const short* cur, short* nxt, int ko) {
    unitA(nxt, ko);
    WAIT_VM2(); BAR();
    loadbv(cur);
    phase(cur, 0);
    unitB(nxt, ko);
    phase(cur, 1);
    phase(cur, 2);
    phase(cur, 3);
    BAR();
  };

  short* bb0 = lds;
  short* bb1 = lds + 16384;
  const int NT = 12;  // K = 768
  unitA(bb0, 0); unitB(bb0, 0);
  int t = 0;
  for (; t + 2 < NT; t += 2) {
    TILE(bb0, bb1, (t + 1) << 6);
    TILE(bb1, bb0, (t + 2) << 6);
  }
  TILE(bb0, bb1, (t + 1) << 6);
  WAIT_VM0(); BAR();
  loadbv(bb1);
  phase(bb1, 0); phase(bb1, 1); phase(bb1, 2); phase(bb1, 3);

#pragma unroll
  for (int mt = 0; mt < 4; mt++) {
    const int gm = m0 + wm + (mt << 4) + r;
    const int gnb = n0 + wn + (q << 2);
    s16x4 p;
    if (MODE == 0) {
      f32x4 b4 = *(const f32x4*)(bias + gnb);
      s16x4 an4 = *(const s16x4*)(an + (long)gm * 768 + gnb);
#pragma unroll
      for (int e = 0; e < 4; e++)
        p[e] = f2bf(sigmoidf_(acc1[mt][e] + b4[e]) * bf2f(an4[e]) +
                    acc2[mt][e]);
    } else {
#pragma unroll
      for (int e = 0; e < 4; e++) {
        float x = acc1[mt][e];
        p[e] = f2bf(x * sigmoidf_(x) * acc2[mt][e]);
      }
    }
    *(s16x4*)(out + (long)gm * ldO + gnb) = p;
  }
}

template <int EP>
__global__ __launch_bounds__(512, 4) void gemm_bt(
    const short* __restrict__ A, const short* __restrict__ W,
    const float* __restrict__ bias, void* __restrict__ Cout,
    const float* __restrict__ res, const short* __restrict__ gate,
    int K, int ldA, int ldC, int gld) {
  __shared__ short lds[32768];
  dev_gemm_bt<EP>(lds, A, W, bias, Cout, res, gate, K, ldA, ldC, gld);
}

template <int MODE>
__global__ __launch_bounds__(512, 4) void gemm_dual(
    const short* __restrict__ A, const short* __restrict__ W, int woff2,
    const float* __restrict__ bias, const short* __restrict__ an,
    short* __restrict__ out, int ldO) {
  __shared__ short lds[32768];
  dev_gemm_dual<MODE>(lds, A, W, woff2, bias, an, out, ldO);
}

// Fused independent pair: z=0 gates GEMM (sigmoid), z=1 AdaLN#1 dual.
__global__ __launch_bounds__(512, 4) void gemm_pair(
    const short* __restrict__ sbf, const short* __restrict__ wgates,
    const float* __restrict__ bias_g, short* __restrict__ gates,
    const short* __restrict__ sn1, const short* __restrict__ wada1,
    const float* __restrict__ bias_a, const short* __restrict__ an1,
    short* __restrict__ outb) {
  __shared__ short lds[32768];
  if (blockIdx.z == 0)
    dev_gemm_bt<1>(lds, sbf, wgates, bias_g, (void*)gates, nullptr, nullptr,
                   768, 768, 1536, 0);
  else
    dev_gemm_dual<0>(lds, sn1, wada1, 768, bias_a, an1, outb, 768);
}

// ---------------------------------------------------------------------------
// Spatial attention (unchanged)
// ---------------------------------------------------------------------------
__global__ __launch_bounds__(256) void attn_spatial(
    const short* __restrict__ qkvg, const short* __restrict__ zt, short* __restrict__ ogo) {
  __shared__ short sKP[256 * 64];
  __shared__ short sVt[64 * 256];
  const int tid = threadIdx.x;
  const int wave = tid >> 6, lane = tid & 63;
  const int qt = blockIdx.x, h = blockIdx.y, bt = blockIdx.z;
  const int b = bt >> 4;
  const int q0 = qt << 6;
  const long rowbase = (long)bt << 8;
  const int hoff = h << 6;

#pragma unroll
  for (int t = 0; t < 8; t++) {
    int c = (t << 8) + tid;
    int tok = c >> 3, kc = (c & 7) ^ (tok & 7);
    *(s16x8*)(sKP + (c << 3)) =
        *(const s16x8*)(qkvg + (rowbase + tok) * 3072 + 768 + hoff + (kc << 3));
  }
#pragma unroll
  for (int t = 0; t < 8; t++) {
    int u = (t << 8) + tid;
    int tok = u >> 3, dc = u & 7;
    s16x8 v8 = *(const s16x8*)(qkvg + (rowbase + tok) * 3072 + 1536 + hoff + (dc << 3));
#pragma unroll
    for (int e = 0; e < 8; e++) {
      int d = (dc << 3) + e;
      int ch = (tok >> 3) ^ (d & 7);
      sVt[((d << 5) + ch) * 8 + (tok & 7)] = v8[e];
    }
  }
  __syncthreads();

  const int q = lane >> 4, cc = lane & 15;
  f32x4 acc[16];
#pragma unroll
  for (int i = 0; i < 16; i++) acc[i] = (f32x4){0.f, 0.f, 0.f, 0.f};
  {
    const int arow = (wave << 4) + cc;
    const short* qrow = qkvg + (rowbase + q0 + arow) * 3072 + hoff;
#pragma unroll
    for (int ks = 0; ks < 2; ks++) {
      s16x8 av = *(const s16x8*)(qrow + (ks << 5) + (q << 3));
#pragma unroll
      for (int nt = 0; nt < 16; nt++) {
        int tok = (nt << 4) + cc;
        int chb = ((ks << 2) + q) ^ (tok & 7);
        s16x8 bv = *(const s16x8*)(sKP + ((tok << 3) + chb) * 8);
        acc[nt] = MFMA16(av, bv, acc[nt]);
      }
    }
  }
  const short* ztb = zt + (((long)(b * 12 + h) * 256 + q0 + (wave << 4)) << 8);
#pragma unroll
  for (int reg = 0; reg < 4; reg++) {
    int lr = (q << 2) + reg;
    float mx = -3.0e38f;
#pragma unroll
    for (int nt = 0; nt < 16; nt++) {
      float v = acc[nt][reg] * 0.125f + bf2f(ztb[lr * 256 + (nt << 4) + cc]);
      acc[nt][reg] = v;
      mx = fmaxf(mx, v);
    }
    mx = fmaxf(mx, __shfl_xor(mx, 1, 16));
    mx = fmaxf(mx, __shfl_xor(mx, 2, 16));
    mx = fmaxf(mx, __shfl_xor(mx, 4, 16));
    mx = fmaxf(mx, __shfl_xor(mx, 8, 16));
    float sum = 0.f;
#pragma unroll
    for (int nt = 0; nt < 16; nt++) {
      float e = __expf(acc[nt][reg] - mx);
      acc[nt][reg] = e; sum += e;
    }
    sum += __shfl_xor(sum, 1, 16);
    sum += __shfl_xor(sum, 2, 16);
    sum += __shfl_xor(sum, 4, 16);
    sum += __shfl_xor(sum, 8, 16);
    float inv = 1.f / sum;
#pragma unroll
    for (int nt = 0; nt < 16; nt++) acc[nt][reg] *= inv;
  }
  __syncthreads();
#pragma unroll
  for (int nt = 0; nt < 16; nt++) {
#pragma unroll
    for (int reg = 0; reg < 4; reg++) {
      int rP = (wave << 4) + (q << 2) + reg;
      int col = (nt << 4) + cc;
      int ch = (col >> 3) ^ (rP & 7);
      sKP[((rP << 5) + ch) * 8 + (col & 7)] = f2bf(acc[nt][reg]);
    }
  }
  __syncthreads();
  f32x4 oacc[4];
#pragma unroll
  for (int i = 0; i < 4; i++) oacc[i] = (f32x4){0.f, 0.f, 0.f, 0.f};
  const int prow = (wave << 4) + cc;
#pragma unroll
  for (int ksi = 0; ksi < 8; ksi++) {
    int cha = ((ksi << 2) + q) ^ (prow & 7);
    s16x8 pa = *(const s16x8*)(sKP + ((prow << 5) + cha) * 8);
#pragma unroll
    for (int dt = 0; dt < 4; dt++) {
      int d = (dt << 4) + cc;
      int chv = ((ksi << 2) + q) ^ (d & 7);
      s16x8 bv = *(const s16x8*)(sVt + ((d << 5) + chv) * 8);
      oacc[dt] = MFMA16(pa, bv, oacc[dt]);
    }
  }
#pragma unroll
  for (int dt = 0; dt < 4; dt++) {
#pragma unroll
    for (int reg = 0; reg < 4; reg++) {
      int rowt = q0 + (wave << 4) + (q << 2) + reg;
      int dcol = (dt << 4) + cc;
      long grow = rowbase + rowt;
      float gl = bf2f(qkvg[grow * 3072 + 2304 + hoff + dcol]);
      ogo[grow * 768 + hoff + dcol] = f2bf(oacc[dt][reg] * sigmoidf_(gl));
    }
  }
}

// ---------------------------------------------------------------------------
// Temporal attention (unchanged)
// ---------------------------------------------------------------------------
__global__ __launch_bounds__(256) void attn_temporal(
    const short* __restrict__ qkvt, const float* __restrict__ ts,
    const float* __restrict__ decay_raw, short* __restrict__ out) {
  __shared__ short sKV[16 * 1544];
  const int bn = blockIdx.x;
  const int b = bn >> 8, n = bn & 255;
  const int tid = threadIdx.x;
#pragma unroll
  for (int t = 0; t < 12; t++) {
    int u = t * 256 + tid;
    int row = u / 192, cc = u % 192;
    *(s16x8*)(sKV + row * 1544 + cc * 8) =
        *(const s16x8*)(qkvt + ((long)(b * 16 + row) * 256 + n) * 2304 + 768 + cc * 8);
  }
  __syncthreads();
  const int h = tid >> 4, tq = tid & 15;
  if (h < 12) {
    const int hoff = h << 6;
    float dec = log1pf(__expf(decay_raw[h]));
    float tsq = ts[b * 16 + tq];
    s16x8 qv[8];
    const short* qrow = qkvt + ((long)(b * 16 + tq) * 256 + n) * 2304 + hoff;
#pragma unroll
    for (int dc = 0; dc < 8; dc++) qv[dc] = *(const s16x8*)(qrow + dc * 8);
    float sc[16];
#pragma unroll
    for (int tk = 0; tk < 16; tk++) {
      float dot = 0.f;
#pragma unroll
      for (int dc = 0; dc < 8; dc++) {
        s16x8 kv = *(const s16x8*)(sKV + tk * 1544 + hoff + dc * 8);
#pragma unroll
        for (int e = 0; e < 8; e++) dot += bf2f(qv[dc][e]) * bf2f(kv[e]);
      }
      sc[tk] = dot * 0.125f - dec * fabsf(tsq - ts[b * 16 + tk]);
    }
    float mx = sc[0];
#pragma unroll
    for (int tk = 1; tk < 16; tk++) mx = fmaxf(mx, sc[tk]);
    float sum = 0.f;
#pragma unroll
    for (int tk = 0; tk < 16; tk++) { sc[tk] = __expf(sc[tk] - mx); sum += sc[tk]; }
    float inv = 1.f / sum;
    float oa[64];
#pragma unroll
    for (int d = 0; d < 64; d++) oa[d] = 0.f;
#pragma unroll
    for (int tk = 0; tk < 16; tk++) {
      float wgt = sc[tk] * inv;
#pragma unroll
      for (int dc = 0; dc < 8; dc++) {
        s16x8 vv = *(const s16x8*)(sKV + tk * 1544 + 768 + hoff + dc * 8);
#pragma unroll
        for (int e = 0; e < 8; e++) oa[dc * 8 + e] += wgt * bf2f(vv[e]);
      }
    }
    long orow = (long)(b * 16 + tq) * 256 + n;
#pragma unroll
    for (int dc = 0; dc < 8; dc++) {
      s16x8 o8;
#pragma unroll
      for (int e = 0; e < 8; e++) o8[e] = f2bf(oa[dc * 8 + e]);
      *(s16x8*)(out + orow * 768 + hoff + dc * 8) = o8;
    }
  }
}

// ---------------------------------------------------------------------------
// Host launcher
// ---------------------------------------------------------------------------
extern "C" void kernel_launch(void* const* d_in, const int* in_sizes, int n_in,
                              void* d_out, int out_size, void* d_ws, size_t ws_size,
                              hipStream_t stream) {
  (void)in_sizes; (void)n_in; (void)out_size; (void)ws_size;
  const float* a_in      = (const float*)d_in[0];
  const float* s_in      = (const float*)d_in[1];
  const float* bias_in   = (const float*)d_in[2];
  const float* ts        = (const float*)d_in[4];
  const float* ada_snorm = (const float*)d_in[7];
  const float* ada_scale_w = (const float*)d_in[8];
  const float* ada_scale_b = (const float*)d_in[9];
  const float* ada_shift_w = (const float*)d_in[10];
  const float* pb_q_w = (const float*)d_in[11];
  const float* pb_q_b = (const float*)d_in[12];
  const float* pb_k_w = (const float*)d_in[13];
  const float* pb_v_w = (const float*)d_in[14];
  const float* pb_g_w = (const float*)d_in[15];
  const float* pb_o_w = (const float*)d_in[16];
  const float* op_w = (const float*)d_in[17];
  const float* op_b = (const float*)d_in[18];
  const float* tr_snorm = (const float*)d_in[19];
  const float* tr_scale_w = (const float*)d_in[20];
  const float* tr_scale_b = (const float*)d_in[21];
  const float* tr_shift_w = (const float*)d_in[22];
  const float* tr_gate_w = (const float*)d_in[23];
  const float* tr_ab_w = (const float*)d_in[24];
  const float* tr_ba_w = (const float*)d_in[25];
  const float* tr_out_w = (const float*)d_in[26];
  const float* tr_out_b = (const float*)d_in[27];
  const float* tmp_ln_w = (const float*)d_in[28];
  const float* tmp_ln_b = (const float*)d_in[29];
  const float* tmp_q_w = (const float*)d_in[30];
  const float* tmp_q_b = (const float*)d_in[31];
  const float* tmp_k_w = (const float*)d_in[32];
  const float* tmp_v_w = (const float*)d_in[33];
  const float* tmp_decay = (const float*)d_in[34];
  const float* tmp_o_w = (const float*)d_in[35];

  char* ws = (char*)d_ws;
  short* W16 = (short*)ws;
  short* WADA1 = (short*)(ws + OFF_WADA1);
  short* WQKVG = (short*)(ws + OFF_WQKVG);
  short* WO = (short*)(ws + OFF_WO);
  short* WGATES = (short*)(ws + OFF_WGATES);
  short* WTMPQKV = (short*)(ws + OFF_WTMPQKV);
  short* WTMPO = (short*)(ws + OFF_WTMPO);
  short* WADA2 = (short*)(ws + OFF_WADA2);
  short* WTRANS = (short*)(ws + OFF_WTRANS);
  short* WBA = (short*)(ws + OFF_WBA);
  float* BIASB = (float*)(ws + OFF_BIAS);
  short* ZT = (short*)(ws + OFF_ZT);
  short* AN1 = (short*)(ws + OFF_AN1);
  short* SN1 = (short*)(ws + OFF_SN1);
  short* SN2 = (short*)(ws + OFF_SN2);
  short* SBF = (short*)(ws + OFF_SBF);
  short* CADA = (short*)(ws + OFF_CADA);
  short* QKVG = (short*)(ws + OFF_QKVG);
  short* GATES = (short*)(ws + OFF_GATES);
  short* OGO = (short*)(ws + OFF_OGO);
  float* A1F = (float*)(ws + OFF_A1);
  float* OUTF = (float*)d_out;

  // 1: all prep + ln_quad in one dispatch
  prep_all<<<dim3(48, 48, 20), dim3(32, 8, 1), 0, stream>>>(
      ada_scale_w, ada_shift_w, pb_q_w, pb_k_w, pb_v_w, pb_g_w, pb_o_w,
      op_w, tr_out_w, tr_scale_w, tr_shift_w, tr_gate_w, tr_ab_w, tr_ba_w,
      tmp_q_w, tmp_k_w, tmp_v_w, tmp_o_w, W16,
      bias_in, ada_scale_b, pb_q_b, op_b, tr_out_b, tmp_q_b, tr_scale_b,
      BIASB, ZT,
      a_in, s_in, ada_snorm, tr_snorm, AN1, SN1, SN2, SBF);
  // 2: gates GEMM + AdaLN#1 dual fused (independent)
  gemm_pair<<<dim3(12, 64, 2), 512, 0, stream>>>(
      SBF, WGATES, BIASB + 4608, GATES, SN1, WADA1, BIASB + 0, AN1, SBF);
  // 3: qkvg
  gemm_bt<0><<<dim3(24, 64), 512, 0, stream>>>(SBF, WQKVG, BIASB + 1536, QKVG,
                                               nullptr, nullptr, 768, 768, 3072, 0);
  // 4: spatial attention (writes sigmoid(g)*o)
  attn_spatial<<<dim3(4, 12, 32), 256, 0, stream>>>(QKVG, ZT, OGO);
  // 5: a1 = a + gate_op * (go @ o_w)
  gemm_bt<3><<<dim3(6, 64), 512, 0, stream>>>(OGO, WO, nullptr, A1F, a_in, GATES,
                                              768, 768, 768, 1536);
  // 6: h = LN(a1)*w+b
  ln_affine<<<2048, 256, 0, stream>>>(A1F, tmp_ln_w, tmp_ln_b, AN1);
  // 7: temporal qkv
  gemm_bt<0><<<dim3(18, 64), 512, 0, stream>>>(AN1, WTMPQKV, BIASB + 6144, QKVG,
                                               nullptr, nullptr, 768, 768, 2304, 0);
  // 8: temporal attention
  attn_temporal<<<512, 256, 0, stream>>>(QKVG, ts, tmp_decay, OGO);
  // 9: a2 = a1 + tattn @ tmp_o_w   (in place)
  gemm_bt<2><<<dim3(6, 64), 512, 0, stream>>>(OGO, WTMPO, nullptr, A1F, A1F, nullptr,
                                              768, 768, 768, 0);
  // 10: an2 = LN(a2)
  ln_affine<<<2048, 256, 0, stream>>>(A1F, nullptr, nullptr, SN1);
  // 11: AdaLN #2 fused -> b2 in SBF
  gemm_dual<0><<<dim3(12, 64), 512, 0, stream>>>(SN2, WADA2, 768, BIASB + 8448, SN1,
                                                 SBF, 768);
  // 12: transition fused SwiGLU: hid = silu(b2@gate)*(b2@ab) -> CADA
  gemm_dual<1><<<dim3(24, 64), 512, 0, stream>>>(SBF, WTRANS, 1536, nullptr, nullptr,
                                                 CADA, 1536);
  // 13: out = a2 + gate_tr * (hid @ ba_w)
  gemm_bt<3><<<dim3(6, 64), 512, 0, stream>>>(CADA, WBA, nullptr, OUTF, A1F,
                                              GATES + 768, 1536, 1536, 768, 1536);
}

// Round 8
// 581.281 us; speedup vs baseline: 1.0553x; 1.0553x over previous
//
#include <hip/hip_runtime.h>

// ---------------------------------------------------------------------------
// Types / helpers
// ---------------------------------------------------------------------------
typedef short s16x8 __attribute__((ext_vector_type(8)));
typedef short s16x4 __attribute__((ext_vector_type(4)));
typedef float f32x4 __attribute__((ext_vector_type(4)));
typedef __bf16 bf16x8 __attribute__((ext_vector_type(8)));

__device__ __forceinline__ float bf2f(short u) {
  union { unsigned int i; float f; } c;
  c.i = ((unsigned int)(unsigned short)u) << 16;
  return c.f;
}
__device__ __forceinline__ short f2bf(float f) {
  union { float f; unsigned int i; } c; c.f = f;
  unsigned int r = c.i + 0x7FFFu + ((c.i >> 16) & 1u);  // RNE
  return (short)(r >> 16);
}
__device__ __forceinline__ float sigmoidf_(float x) { return 1.f / (1.f + __expf(-x)); }

template <typename T>
__device__ __forceinline__ auto mfma_sel(T a, T b, f32x4 c, int)
    -> decltype(__builtin_amdgcn_mfma_f32_16x16x32_bf16(a, b, c, 0, 0, 0)) {
  return __builtin_amdgcn_mfma_f32_16x16x32_bf16(a, b, c, 0, 0, 0);
}
template <typename T>
__device__ __forceinline__ f32x4 mfma_sel(T a, T b, f32x4 c, long) {
  return __builtin_amdgcn_mfma_f32_16x16x32_bf16(
      __builtin_bit_cast(bf16x8, a), __builtin_bit_cast(bf16x8, b), c, 0, 0, 0);
}
__device__ __forceinline__ f32x4 MFMA16(s16x8 a, s16x8 b, f32x4 c) {
  return mfma_sel(a, b, c, 0);
}

__device__ __forceinline__ void gl2lds16(const void* g, void* l) {
  __builtin_amdgcn_global_load_lds(
      (const __attribute__((address_space(1))) unsigned int*)g,
      (__attribute__((address_space(3))) unsigned int*)l, 16, 0, 0);
}

// Counted-vmcnt pipeline (T4). Per K-tile each thread issues 4 loads in 2
// units of 2. At a tile boundary: outstanding = 4 (current tile) + 2 (next
// tile's unitA, issued just before the wait) -> vmcnt(2) == current tile
// fully landed, next tile's first unit stays in flight.
#define WAIT_VM2()  asm volatile("s_waitcnt vmcnt(2)" ::: "memory")
#define WAIT_VM0()  asm volatile("s_waitcnt vmcnt(0)" ::: "memory")
#define BAR()       __builtin_amdgcn_s_barrier()
#define PRIO1()     __builtin_amdgcn_s_setprio(1)
#define PRIO0()     __builtin_amdgcn_s_setprio(0)

// Bijective XCD-chunked swizzle (m204).
__device__ __forceinline__ int xcd_swz(int id, int nwg) {
  int q = nwg >> 3, r = nwg & 7;
  int xcd = id & 7, idx = id >> 3;
  return (xcd < r ? xcd * (q + 1) : r * (q + 1) + (xcd - r) * q) + idx;
}

// Superblocks of 8 m-rows, m fastest (B-panel L2-hot). gridDim.y == 64.
__device__ __forceinline__ void tile_mn(int nid, int gx, int* mt, int* nt) {
  int sb = nid / (gx << 3);
  int rem = nid - sb * (gx << 3);
  *mt = (sb << 3) + (rem & 7);
  *nt = rem >> 3;
}

// ---------------------------------------------------------------------------
// Workspace layout (byte offsets)
// ---------------------------------------------------------------------------
#define OFF_WADA1    0u
#define OFF_WQKVG    2359296u
#define OFF_WO       7077888u
#define OFF_WGATES   8257536u
#define OFF_WTMPQKV  10616832u
#define OFF_WTMPO    14155776u
#define OFF_WADA2    15335424u
#define OFF_WTRANS   17694720u
#define OFF_WBA      22413312u
#define OFF_BIAS     24772608u
#define OFF_ZT       24812544u
#define OFF_AN1      31104000u
#define OFF_SN1      43686912u
#define OFF_SN2      56269824u
#define OFF_SBF      68852736u
#define OFF_CADA     81435648u
#define OFF_QKVG     106601472u
#define OFF_GATES    156933120u
#define OFF_OGO      182098944u
#define OFF_A1       194681856u

// ---------------------------------------------------------------------------
// Mega prep kernel — flat 1-D grid of exactly 5623 blocks (zero idle):
//   [0, 3024)        : 18 weight transposes, 64x64 tiles, f32x4 loads +
//                      s16x4 stores (128B-aligned contiguous writes)
//   [3024, 3536)     : zt transpose (512 blocks)
//   [3536, 3575)     : bias assembly (39 blocks)
//   [3575, 5623)     : ln_quad, 4 rows/block (2048 blocks)
// ---------------------------------------------------------------------------
#define PREP_NBLK 5623

__global__ __launch_bounds__(256) void prep_all(
    const float* p0, const float* p1, const float* p2, const float* p3,
    const float* p4, const float* p5, const float* p6, const float* p7,
    const float* p8, const float* p9, const float* p10, const float* p11,
    const float* p12, const float* p13, const float* p14, const float* p15,
    const float* p16, const float* p17, short* wsb,
    const float* __restrict__ zsrc, const float* __restrict__ ada_scale_b,
    const float* __restrict__ pb_q_b, const float* __restrict__ op_b,
    const float* __restrict__ tr_out_b, const float* __restrict__ tmp_q_b,
    const float* __restrict__ tr_scale_b,
    float* __restrict__ biasbuf, short* __restrict__ zt,
    const float* __restrict__ a_in, const float* __restrict__ s_in,
    const float* __restrict__ lnw1, const float* __restrict__ lnw2,
    short* __restrict__ an1, short* __restrict__ sn1, short* __restrict__ sn2,
    short* __restrict__ sbf) {
  const int tid = threadIdx.x;
  const int bid = blockIdx.x;
  struct E { int K, N, dst; };
  const E tab[18] = {
      {768, 768, 0},        {768, 768, 589824},
      {768, 768, 1179648},  {768, 768, 1769472},
      {768, 768, 2359296},  {768, 768, 2949120},
      {768, 768, 3538944},
      {768, 768, 4128768},  {768, 768, 4718592},
      {768, 768, 7667712},  {768, 768, 8257536},
      {768, 1536, 8847360}, {768, 1536, 10027008},
      {1536, 768, 11206656},
      {768, 768, 5308416},  {768, 768, 5898240}, {768, 768, 6488064},
      {768, 768, 7077888}};
  if (bid < 3024) {
    // ---- weight transpose: src [K][N] fp32 -> dst [N][K] bf16, 64x64 tile
    int zidx = 0, base = 0;
    for (;;) {
      int tiles = (tab[zidx].K >> 6) * (tab[zidx].N >> 6);
      if (bid < base + tiles) break;
      base += tiles; ++zidx;
    }
    const int K = tab[zidx].K, N = tab[zidx].N;
    const int ntx = N >> 6;
    const int local = bid - base;
    const int n0 = (local % ntx) << 6;
    const int k0 = (local / ntx) << 6;
    const float* src;
    switch (zidx) {
      case 0: src = p0; break;  case 1: src = p1; break;
      case 2: src = p2; break;  case 3: src = p3; break;
      case 4: src = p4; break;  case 5: src = p5; break;
      case 6: src = p6; break;  case 7: src = p7; break;
      case 8: src = p8; break;  case 9: src = p9; break;
      case 10: src = p10; break; case 11: src = p11; break;
      case 12: src = p12; break; case 13: src = p13; break;
      case 14: src = p14; break; case 15: src = p15; break;
      case 16: src = p16; break; default: src = p17; break;
    }
    short* dst = wsb + tab[zidx].dst;
    __shared__ float t[64][65];
#pragma unroll
    for (int j = 0; j < 4; j++) {
      int idx = (j << 8) + tid;
      int kr = idx >> 4, nc = (idx & 15) << 2;
      f32x4 v = *(const f32x4*)(src + (long)(k0 + kr) * N + n0 + nc);
      t[nc][kr] = v[0]; t[nc + 1][kr] = v[1];
      t[nc + 2][kr] = v[2]; t[nc + 3][kr] = v[3];
    }
    __syncthreads();
#pragma unroll
    for (int j = 0; j < 4; j++) {
      int idx = (j << 8) + tid;
      int nr = idx >> 4, kc = (idx & 15) << 2;
      s16x4 o;
#pragma unroll
      for (int e = 0; e < 4; e++) o[e] = f2bf(t[nr][kc + e]);
      *(s16x4*)(dst + (long)(n0 + nr) * K + k0 + kc) = o;
    }
  } else if (bid < 3536) {
    // ---- zt transpose (512 blocks)
    const int bid2 = bid - 3024;
    const int b = bid2 >> 8, qq = bid2 & 255;
    const float* src = zsrc + (long)bid2 * 3072 + tid * 12;
    f32x4 v0 = *(const f32x4*)(src);
    f32x4 v1 = *(const f32x4*)(src + 4);
    f32x4 v2 = *(const f32x4*)(src + 8);
    float vals[12] = {v0[0], v0[1], v0[2], v0[3], v1[0], v1[1],
                      v1[2], v1[3], v2[0], v2[1], v2[2], v2[3]};
#pragma unroll
    for (int h = 0; h < 12; h++)
      zt[(((long)(b * 12 + h) * 256 + qq) << 8) + tid] = f2bf(vals[h]);
  } else if (bid < 3575) {
    // ---- bias assembly (39 blocks, 9984 floats)
    int j = (bid - 3536) * 256 + tid;
    if (j < 9984) {
      float v;
      if (j < 1536) v = (j < 768) ? ada_scale_b[j] : 0.f;
      else if (j < 4608) { int jj = j - 1536; v = (jj < 768) ? pb_q_b[jj] : 0.f; }
      else if (j < 6144) { int jj = j - 4608; v = (jj < 768) ? op_b[jj] : tr_out_b[jj - 768]; }
      else if (j < 8448) { int jj = j - 6144; v = (jj < 768) ? tmp_q_b[jj] : 0.f; }
      else { int jj = j - 8448; v = (jj < 768) ? tr_scale_b[jj] : 0.f; }
      biasbuf[j] = v;
    }
  } else {
    // ---- ln_quad (2048 blocks, 4 rows each: wave-per-row)
    const int bid3 = bid - 3575;
    const int wave = tid >> 6, lane = tid & 63;
    const int row = (bid3 << 2) + wave;
    const float* ar = a_in + (long)row * 768;
    const float* sr = s_in + (long)row * 768;
    f32x4 av[3], sv[3];
    float s0 = 0, s1 = 0, s2 = 0, s3 = 0;
#pragma unroll
    for (int k = 0; k < 3; k++) {
      int col = (lane << 2) + (k << 8);
      av[k] = *(const f32x4*)(ar + col);
      sv[k] = *(const f32x4*)(sr + col);
#pragma unroll
      for (int e = 0; e < 4; e++) {
        s0 += av[k][e]; s1 += av[k][e] * av[k][e];
        s2 += sv[k][e]; s3 += sv[k][e] * sv[k][e];
      }
    }
#pragma unroll
    for (int o = 32; o; o >>= 1) {
      s0 += __shfl_xor(s0, o, 64); s1 += __shfl_xor(s1, o, 64);
      s2 += __shfl_xor(s2, o, 64); s3 += __shfl_xor(s3, o, 64);
    }
    const float inv768 = 1.f / 768.f;
    float ma = s0 * inv768, va = s1 * inv768 - ma * ma;
    float ia = rsqrtf(va + 1e-5f);
    float ms = s2 * inv768, vs = s3 * inv768 - ms * ms;
    float is_ = rsqrtf(vs + 1e-5f);
#pragma unroll
    for (int k = 0; k < 3; k++) {
      int col = (lane << 2) + (k << 8);
      long o = (long)row * 768 + col;
      s16x4 o1, o2, o3, o4;
#pragma unroll
      for (int e = 0; e < 4; e++) {
        o1[e] = f2bf((av[k][e] - ma) * ia);
        float sn = (sv[k][e] - ms) * is_;
        o2[e] = f2bf(sn * lnw1[col + e]);
        o3[e] = f2bf(sn * lnw2[col + e]);
        o4[e] = f2bf(sv[k][e]);
      }
      *(s16x4*)(an1 + o) = o1;
      *(s16x4*)(sn1 + o) = o2;
      *(s16x4*)(sn2 + o) = o3;
      *(s16x4*)(sbf + o) = o4;
    }
  }
}

// ---------------------------------------------------------------------------
// ln_affine (unchanged)
// ---------------------------------------------------------------------------
__global__ __launch_bounds__(256) void ln_affine(
    const float* __restrict__ in, const float* __restrict__ w,
    const float* __restrict__ b, short* __restrict__ out) {
  const int wave = threadIdx.x >> 6, lane = threadIdx.x & 63;
  const int row = (blockIdx.x << 2) + wave;
  const float* xr = in + (long)row * 768;
  f32x4 xv[3];
  float s0 = 0, s1 = 0;
#pragma unroll
  for (int k = 0; k < 3; k++) {
    int col = (lane << 2) + (k << 8);
    xv[k] = *(const f32x4*)(xr + col);
#pragma unroll
    for (int e = 0; e < 4; e++) { s0 += xv[k][e]; s1 += xv[k][e] * xv[k][e]; }
  }
#pragma unroll
  for (int o = 32; o; o >>= 1) { s0 += __shfl_xor(s0, o, 64); s1 += __shfl_xor(s1, o, 64); }
  const float inv768 = 1.f / 768.f;
  float m = s0 * inv768, v = s1 * inv768 - m * m;
  float inv = rsqrtf(v + 1e-5f);
#pragma unroll
  for (int k = 0; k < 3; k++) {
    int col = (lane << 2) + (k << 8);
    s16x4 p;
#pragma unroll
    for (int e = 0; e < 4; e++) {
      float y = (xv[k][e] - m) * inv;
      if (w) y = y * w[col + e] + b[col + e];
      p[e] = f2bf(y);
    }
    *(s16x4*)(out + (long)row * 768 + col) = p;
  }
}

// ---------------------------------------------------------------------------
// GEMM engine v3 — 128(m)x128(n) tile, 512 threads (8 waves, 2m x 4n),
// 64 KB double-buffered LDS, phase-split pipeline with counted vmcnt.
// EP: 0 bf16(+bias), 1 bf16 sigmoid(+bias), 2 f32 res+acc, 3 f32 res+gate*acc
// ---------------------------------------------------------------------------
template <int EP>
__device__ __forceinline__ void dev_gemm_bt(
    short* lds,
    const short* __restrict__ A, const short* __restrict__ W,
    const float* __restrict__ bias, void* __restrict__ Cout,
    const float* __restrict__ res, const short* __restrict__ gate,
    int K, int ldA, int ldC, int gld) {
  const int tid = threadIdx.x;           // 0..511
  const int wave = tid >> 6;             // 0..7
  const int lane = tid & 63;
  const int gx = gridDim.x;
  const int nid = xcd_swz(blockIdx.y * gx + blockIdx.x, gx * gridDim.y);
  int mt_, nt_;
  tile_mn(nid, gx, &mt_, &nt_);
  const int m0 = mt_ << 7;
  const int n0 = nt_ << 7;
  const int wm = (wave & 1) << 6;        // 0,64
  const int wn = (wave >> 1) << 5;       // 0,32,64,96
  const int q = lane >> 4, r = lane & 15;
  f32x4 acc[4][2];
#pragma unroll
  for (int i = 0; i < 4; i++)
#pragma unroll
    for (int j = 0; j < 2; j++) acc[i][j] = (f32x4){0.f, 0.f, 0.f, 0.f};

  const short* pA[2];
  const short* pB[2];
#pragma unroll
  for (int j = 0; j < 2; j++) {
    int c = (j << 9) + tid;
    int m = c >> 3, kc = (c & 7) ^ (m & 7);
    pA[j] = A + (long)(m0 + m) * ldA + (kc << 3);
    pB[j] = W + (long)(n0 + m) * K + (kc << 3);
  }
  const int lA0 = (wave << 9);
  const int lA1 = (1 << 12) + (wave << 9);
  const int lB0 = 8192 + (wave << 9);
  const int lB1 = 8192 + (1 << 12) + (wave << 9);

  int offA[4][2], offB[2][2];
#pragma unroll
  for (int p = 0; p < 4; p++)
#pragma unroll
    for (int ks = 0; ks < 2; ks++) {
      int row = wm + (p << 4) + r;
      offA[p][ks] = ((row << 3) + (((ks << 2) + q) ^ (row & 7))) << 3;
    }
#pragma unroll
  for (int ks = 0; ks < 2; ks++)
#pragma unroll
    for (int nt = 0; nt < 2; nt++) {
      int row = wn + (nt << 4) + r;
      offB[ks][nt] = 8192 + (((row << 3) + (((ks << 2) + q) ^ (row & 7))) << 3);
    }

  auto unitA = [&](short* buf, int ko) {
    gl2lds16(pA[0] + ko, buf + lA0);
    gl2lds16(pA[1] + ko, buf + lA1);
  };
  auto unitB = [&](short* buf, int ko) {
    gl2lds16(pB[0] + ko, buf + lB0);
    gl2lds16(pB[1] + ko, buf + lB1);
  };

  s16x8 bv[2][2];
  auto loadbv = [&](const short* buf) {
#pragma unroll
    for (int ks = 0; ks < 2; ks++)
#pragma unroll
      for (int nt = 0; nt < 2; nt++)
        bv[ks][nt] = *(const s16x8*)(buf + offB[ks][nt]);
  };
  auto phase = [&](const short* buf, int p) {
    s16x8 a0 = *(const s16x8*)(buf + offA[p][0]);
    s16x8 a1 = *(const s16x8*)(buf + offA[p][1]);
    PRIO1();
#pragma unroll
    for (int nt = 0; nt < 2; nt++) {
      acc[p][nt] = MFMA16(bv[0][nt], a0, acc[p][nt]);
      acc[p][nt] = MFMA16(bv[1][nt], a1, acc[p][nt]);
    }
    PRIO0();
  };

  auto TILE = [&](const short* cur, short* nxt, int ko) {
    unitA(nxt, ko);
    WAIT_VM2(); BAR();
    loadbv(cur);
    phase(cur, 0);
    unitB(nxt, ko);
    phase(cur, 1);
    phase(cur, 2);
    phase(cur, 3);
    BAR();
  };

  short* b0 = lds;
  short* b1 = lds + 16384;
  const int NT = K >> 6;  // even (12 or 24)
  unitA(b0, 0); unitB(b0, 0);
  int t = 0;
  for (; t + 2 < NT; t += 2) {
    TILE(b0, b1, (t + 1) << 6);
    TILE(b1, b0, (t + 2) << 6);
  }
  TILE(b0, b1, (t + 1) << 6);  // computes tile NT-2, stages NT-1
  WAIT_VM0(); BAR();
  loadbv(b1);
  phase(b1, 0); phase(b1, 1); phase(b1, 2); phase(b1, 3);

#pragma unroll
  for (int mt = 0; mt < 4; mt++) {
    const int gm = m0 + wm + (mt << 4) + r;
#pragma unroll
    for (int nt = 0; nt < 2; nt++) {
      const int gnb = n0 + wn + (nt << 4) + (q << 2);
      f32x4 v = acc[mt][nt];
      if (bias) {
        f32x4 b4 = *(const f32x4*)(bias + gnb);
        v += b4;
      }
      long o = (long)gm * ldC + gnb;
      if (EP == 0) {
        s16x4 p;
#pragma unroll
        for (int e = 0; e < 4; e++) p[e] = f2bf(v[e]);
        *(s16x4*)((short*)Cout + o) = p;
      } else if (EP == 1) {
        s16x4 p;
#pragma unroll
        for (int e = 0; e < 4; e++) p[e] = f2bf(sigmoidf_(v[e]));
        *(s16x4*)((short*)Cout + o) = p;
      } else if (EP == 2) {
        f32x4 r4 = *(const f32x4*)(res + o);
        *(f32x4*)((float*)Cout + o) = r4 + v;
      } else {
        f32x4 r4 = *(const f32x4*)(res + o);
        s16x4 g4 = *(const s16x4*)(gate + (long)gm * gld + gnb);
        f32x4 out;
#pragma unroll
        for (int e = 0; e < 4; e++) out[e] = r4[e] + bf2f(g4[e]) * v[e];
        *(f32x4*)((float*)Cout + o) = out;
      }
    }
  }
}

// Dual GEMM v3 — 128(m) x (64|64)(n) halves, same pipeline.
// MODE 0 (adaln): out = bf16( sigmoid(c1+bias)*an + c2 ); MODE 1: silu(c1)*c2
template <int MODE>
__device__ __forceinline__ void dev_gemm_dual(
    short* lds,
    const short* __restrict__ A, const short* __restrict__ W, int woff2,
    const float* __restrict__ bias, const short* __restrict__ an,
    short* __restrict__ out, int ldO) {
  const int tid = threadIdx.x;
  const int wave = tid >> 6, lane = tid & 63;
  const int gx = gridDim.x;
  const int nid = xcd_swz(blockIdx.y * gx + blockIdx.x, gx * gridDim.y);
  int mt_, nt_;
  tile_mn(nid, gx, &mt_, &nt_);
  const int m0 = mt_ << 7;
  const int n0 = nt_ << 6;               // 64-col tiles per half
  const int wm = (wave & 1) << 6;        // 0,64
  const int wn = (wave >> 1) << 4;       // 0,16,32,48
  const int q = lane >> 4, r = lane & 15;
  f32x4 acc1[4], acc2[4];
#pragma unroll
  for (int i = 0; i < 4; i++) {
    acc1[i] = (f32x4){0.f, 0.f, 0.f, 0.f};
    acc2[i] = (f32x4){0.f, 0.f, 0.f, 0.f};
  }

  const short* pA[2];
  const short* pB1;
  const short* pB2;
#pragma unroll
  for (int j = 0; j < 2; j++) {
    int c = (j << 9) + tid;
    int m = c >> 3, kc = (c & 7) ^ (m & 7);
    pA[j] = A + (long)(m0 + m) * 768 + (kc << 3);
  }
  {
    int m = tid >> 3, kc = (tid & 7) ^ (m & 7);
    pB1 = W + (long)(n0 + m) * 768 + (kc << 3);
    pB2 = W + (long)(woff2 + n0 + m) * 768 + (kc << 3);
  }
  const int lA0 = (wave << 9);
  const int lA1 = (1 << 12) + (wave << 9);
  const int lB1o = 8192 + (wave << 9);
  const int lB2o = 12288 + (wave << 9);

  int offA[4][2], offB[2];
#pragma unroll
  for (int p = 0; p < 4; p++)
#pragma unroll
    for (int ks = 0; ks < 2; ks++) {
      int row = wm + (p << 4) + r;
      offA[p][ks] = ((row << 3) + (((ks << 2) + q) ^ (row & 7))) << 3;
    }
#pragma unroll
  for (int ks = 0; ks < 2; ks++) {
    int row = wn + r;
    offB[ks] = ((row << 3) + (((ks << 2) + q) ^ (row & 7))) << 3;
  }

  auto unitA = [&](short* buf, int ko) {
    gl2lds16(pA[0] + ko, buf + lA0);
    gl2lds16(pA[1] + ko, buf + lA1);
  };
  auto unitB = [&](short* buf, int ko) {
    gl2lds16(pB1 + ko, buf + lB1o);
    gl2lds16(pB2 + ko, buf + lB2o);
  };

  s16x8 b1v[2], b2v[2];
  auto loadbv = [&](const short* buf) {
#pragma unroll
    for (int ks = 0; ks < 2; ks++) {
      b1v[ks] = *(const s16x8*)(buf + 8192 + offB[ks]);
      b2v[ks] = *(const s16x8*)(buf + 12288 + offB[ks]);
    }
  };
  auto phase = [&](const short* buf, int p) {
    s16x8 a0 = *(const s16x8*)(buf + offA[p][0]);
    s16x8 a1 = *(const s16x8*)(buf + offA[p][1]);
    PRIO1();
    acc1[p] = MFMA16(b1v[0], a0, acc1[p]);
    acc1[p] = MFMA16(b1v[1], a1, acc1[p]);
    acc2[p] = MFMA16(b2v[0], a0, acc2[p]);
    acc2[p] = MFMA16(b2v[1], a1, acc2[p]);
    PRIO0();
  };
  auto TILE = [&](const short* cur, short* nxt, int ko) {
    unitA(nxt, ko);
    WAIT_VM2(); BAR();
    loadbv(cur);
    phase(cur, 0);
    unitB(nxt, ko);
    phase(cur, 1);
    phase(cur, 2);
    phase(cur, 3);
    BAR();
  };

  short* bb0 = lds;
  short* bb1 = lds + 16384;
  const int NT = 12;  // K = 768
  unitA(bb0, 0); unitB(bb0, 0);
  int t = 0;
  for (; t + 2 < NT; t += 2) {
    TILE(bb0, bb1, (t + 1) << 6);
    TILE(bb1, bb0, (t + 2) << 6);
  }
  TILE(bb0, bb1, (t + 1) << 6);
  WAIT_VM0(); BAR();
  loadbv(bb1);
  phase(bb1, 0); phase(bb1, 1); phase(bb1, 2); phase(bb1, 3);

#pragma unroll
  for (int mt = 0; mt < 4; mt++) {
    const int gm = m0 + wm + (mt << 4) + r;
    const int gnb = n0 + wn + (q << 2);
    s16x4 p;
    if (MODE == 0) {
      f32x4 b4 = *(const f32x4*)(bias + gnb);
      s16x4 an4 = *(const s16x4*)(an + (long)gm * 768 + gnb);
#pragma unroll
      for (int e = 0; e < 4; e++)
        p[e] = f2bf(sigmoidf_(acc1[mt][e] + b4[e]) * bf2f(an4[e]) +
                    acc2[mt][e]);
    } else {
#pragma unroll
      for (int e = 0; e < 4; e++) {
        float x = acc1[mt][e];
        p[e] = f2bf(x * sigmoidf_(x) * acc2[mt][e]);
      }
    }
    *(s16x4*)(out + (long)gm * ldO + gnb) = p;
  }
}

template <int EP>
__global__ __launch_bounds__(512, 4) void gemm_bt(
    const short* __restrict__ A, const short* __restrict__ W,
    const float* __restrict__ bias, void* __restrict__ Cout,
    const float* __restrict__ res, const short* __restrict__ gate,
    int K, int ldA, int ldC, int gld) {
  __shared__ short lds[32768];
  dev_gemm_bt<EP>(lds, A, W, bias, Cout, res, gate, K, ldA, ldC, gld);
}

template <int MODE>
__global__ __launch_bounds__(512, 4) void gemm_dual(
    const short* __restrict__ A, const short* __restrict__ W, int woff2,
    const float* __restrict__ bias, const short* __restrict__ an,
    short* __restrict__ out, int ldO) {
  __shared__ short lds[32768];
  dev_gemm_dual<MODE>(lds, A, W, woff2, bias, an, out, ldO);
}

// Fused independent pair: z=0 gates GEMM (sigmoid), z=1 AdaLN#1 dual.
__global__ __launch_bounds__(512, 4) void gemm_pair(
    const short* __restrict__ sbf, const short* __restrict__ wgates,
    const float* __restrict__ bias_g, short* __restrict__ gates,
    const short* __restrict__ sn1, const short* __restrict__ wada1,
    const float* __restrict__ bias_a, const short* __restrict__ an1,
    short* __restrict__ outb) {
  __shared__ short lds[32768];
  if (blockIdx.z == 0)
    dev_gemm_bt<1>(lds, sbf, wgates, bias_g, (void*)gates, nullptr, nullptr,
                   768, 768, 1536, 0);
  else
    dev_gemm_dual<0>(lds, sn1, wada1, 768, bias_a, an1, outb, 768);
}

// ---------------------------------------------------------------------------
// Spatial attention (unchanged)
// ---------------------------------------------------------------------------
__global__ __launch_bounds__(256) void attn_spatial(
    const short* __restrict__ qkvg, const short* __restrict__ zt, short* __restrict__ ogo) {
  __shared__ short sKP[256 * 64];
  __shared__ short sVt[64 * 256];
  const int tid = threadIdx.x;
  const int wave = tid >> 6, lane = tid & 63;
  const int qt = blockIdx.x, h = blockIdx.y, bt = blockIdx.z;
  const int b = bt >> 4;
  const int q0 = qt << 6;
  const long rowbase = (long)bt << 8;
  const int hoff = h << 6;

#pragma unroll
  for (int t = 0; t < 8; t++) {
    int c = (t << 8) + tid;
    int tok = c >> 3, kc = (c & 7) ^ (tok & 7);
    *(s16x8*)(sKP + (c << 3)) =
        *(const s16x8*)(qkvg + (rowbase + tok) * 3072 + 768 + hoff + (kc << 3));
  }
#pragma unroll
  for (int t = 0; t < 8; t++) {
    int u = (t << 8) + tid;
    int tok = u >> 3, dc = u & 7;
    s16x8 v8 = *(const s16x8*)(qkvg + (rowbase + tok) * 3072 + 1536 + hoff + (dc << 3));
#pragma unroll
    for (int e = 0; e < 8; e++) {
      int d = (dc << 3) + e;
      int ch = (tok >> 3) ^ (d & 7);
      sVt[((d << 5) + ch) * 8 + (tok & 7)] = v8[e];
    }
  }
  __syncthreads();

  const int q = lane >> 4, cc = lane & 15;
  f32x4 acc[16];
#pragma unroll
  for (int i = 0; i < 16; i++) acc[i] = (f32x4){0.f, 0.f, 0.f, 0.f};
  {
    const int arow = (wave << 4) + cc;
    const short* qrow = qkvg + (rowbase + q0 + arow) * 3072 + hoff;
#pragma unroll
    for (int ks = 0; ks < 2; ks++) {
      s16x8 av = *(const s16x8*)(qrow + (ks << 5) + (q << 3));
#pragma unroll
      for (int nt = 0; nt < 16; nt++) {
        int tok = (nt << 4) + cc;
        int chb = ((ks << 2) + q) ^ (tok & 7);
        s16x8 bv = *(const s16x8*)(sKP + ((tok << 3) + chb) * 8);
        acc[nt] = MFMA16(av, bv, acc[nt]);
      }
    }
  }
  const short* ztb = zt + (((long)(b * 12 + h) * 256 + q0 + (wave << 4)) << 8);
#pragma unroll
  for (int reg = 0; reg < 4; reg++) {
    int lr = (q << 2) + reg;
    float mx = -3.0e38f;
#pragma unroll
    for (int nt = 0; nt < 16; nt++) {
      float v = acc[nt][reg] * 0.125f + bf2f(ztb[lr * 256 + (nt << 4) + cc]);
      acc[nt][reg] = v;
      mx = fmaxf(mx, v);
    }
    mx = fmaxf(mx, __shfl_xor(mx, 1, 16));
    mx = fmaxf(mx, __shfl_xor(mx, 2, 16));
    mx = fmaxf(mx, __shfl_xor(mx, 4, 16));
    mx = fmaxf(mx, __shfl_xor(mx, 8, 16));
    float sum = 0.f;
#pragma unroll
    for (int nt = 0; nt < 16; nt++) {
      float e = __expf(acc[nt][reg] - mx);
      acc[nt][reg] = e; sum += e;
    }
    sum += __shfl_xor(sum, 1, 16);
    sum += __shfl_xor(sum, 2, 16);
    sum += __shfl_xor(sum, 4, 16);
    sum += __shfl_xor(sum, 8, 16);
    float inv = 1.f / sum;
#pragma unroll
    for (int nt = 0; nt < 16; nt++) acc[nt][reg] *= inv;
  }
  __syncthreads();
#pragma unroll
  for (int nt = 0; nt < 16; nt++) {
#pragma unroll
    for (int reg = 0; reg < 4; reg++) {
      int rP = (wave << 4) + (q << 2) + reg;
      int col = (nt << 4) + cc;
      int ch = (col >> 3) ^ (rP & 7);
      sKP[((rP << 5) + ch) * 8 + (col & 7)] = f2bf(acc[nt][reg]);
    }
  }
  __syncthreads();
  f32x4 oacc[4];
#pragma unroll
  for (int i = 0; i < 4; i++) oacc[i] = (f32x4){0.f, 0.f, 0.f, 0.f};
  const int prow = (wave << 4) + cc;
#pragma unroll
  for (int ksi = 0; ksi < 8; ksi++) {
    int cha = ((ksi << 2) + q) ^ (prow & 7);
    s16x8 pa = *(const s16x8*)(sKP + ((prow << 5) + cha) * 8);
#pragma unroll
    for (int dt = 0; dt < 4; dt++) {
      int d = (dt << 4) + cc;
      int chv = ((ksi << 2) + q) ^ (d & 7);
      s16x8 bv = *(const s16x8*)(sVt + ((d << 5) + chv) * 8);
      oacc[dt] = MFMA16(pa, bv, oacc[dt]);
    }
  }
#pragma unroll
  for (int dt = 0; dt < 4; dt++) {
#pragma unroll
    for (int reg = 0; reg < 4; reg++) {
      int rowt = q0 + (wave << 4) + (q << 2) + reg;
      int dcol = (dt << 4) + cc;
      long grow = rowbase + rowt;
      float gl = bf2f(qkvg[grow * 3072 + 2304 + hoff + dcol]);
      ogo[grow * 768 + hoff + dcol] = f2bf(oacc[dt][reg] * sigmoidf_(gl));
    }
  }
}

// ---------------------------------------------------------------------------
// Temporal attention (unchanged)
// ---------------------------------------------------------------------------
__global__ __launch_bounds__(256) void attn_temporal(
    const short* __restrict__ qkvt, const float* __restrict__ ts,
    const float* __restrict__ decay_raw, short* __restrict__ out) {
  __shared__ short sKV[16 * 1544];
  const int bn = blockIdx.x;
  const int b = bn >> 8, n = bn & 255;
  const int tid = threadIdx.x;
#pragma unroll
  for (int t = 0; t < 12; t++) {
    int u = t * 256 + tid;
    int row = u / 192, cc = u % 192;
    *(s16x8*)(sKV + row * 1544 + cc * 8) =
        *(const s16x8*)(qkvt + ((long)(b * 16 + row) * 256 + n) * 2304 + 768 + cc * 8);
  }
  __syncthreads();
  const int h = tid >> 4, tq = tid & 15;
  if (h < 12) {
    const int hoff = h << 6;
    float dec = log1pf(__expf(decay_raw[h]));
    float tsq = ts[b * 16 + tq];
    s16x8 qv[8];
    const short* qrow = qkvt + ((long)(b * 16 + tq) * 256 + n) * 2304 + hoff;
#pragma unroll
    for (int dc = 0; dc < 8; dc++) qv[dc] = *(const s16x8*)(qrow + dc * 8);
    float sc[16];
#pragma unroll
    for (int tk = 0; tk < 16; tk++) {
      float dot = 0.f;
#pragma unroll
      for (int dc = 0; dc < 8; dc++) {
        s16x8 kv = *(const s16x8*)(sKV + tk * 1544 + hoff + dc * 8);
#pragma unroll
        for (int e = 0; e < 8; e++) dot += bf2f(qv[dc][e]) * bf2f(kv[e]);
      }
      sc[tk] = dot * 0.125f - dec * fabsf(tsq - ts[b * 16 + tk]);
    }
    float mx = sc[0];
#pragma unroll
    for (int tk = 1; tk < 16; tk++) mx = fmaxf(mx, sc[tk]);
    float sum = 0.f;
#pragma unroll
    for (int tk = 0; tk < 16; tk++) { sc[tk] = __expf(sc[tk] - mx); sum += sc[tk]; }
    float inv = 1.f / sum;
    float oa[64];
#pragma unroll
    for (int d = 0; d < 64; d++) oa[d] = 0.f;
#pragma unroll
    for (int tk = 0; tk < 16; tk++) {
      float wgt = sc[tk] * inv;
#pragma unroll
      for (int dc = 0; dc < 8; dc++) {
        s16x8 vv = *(const s16x8*)(sKV + tk * 1544 + 768 + hoff + dc * 8);
#pragma unroll
        for (int e = 0; e < 8; e++) oa[dc * 8 + e] += wgt * bf2f(vv[e]);
      }
    }
    long orow = (long)(b * 16 + tq) * 256 + n;
#pragma unroll
    for (int dc = 0; dc < 8; dc++) {
      s16x8 o8;
#pragma unroll
      for (int e = 0; e < 8; e++) o8[e] = f2bf(oa[dc * 8 + e]);
      *(s16x8*)(out + orow * 768 + hoff + dc * 8) = o8;
    }
  }
}

// ---------------------------------------------------------------------------
// Host launcher
// ---------------------------------------------------------------------------
extern "C" void kernel_launch(void* const* d_in, const int* in_sizes, int n_in,
                              void* d_out, int out_size, void* d_ws, size_t ws_size,
                              hipStream_t stream) {
  (void)in_sizes; (void)n_in; (void)out_size; (void)ws_size;
  const float* a_in      = (const float*)d_in[0];
  const float* s_in      = (const float*)d_in[1];
  const float* bias_in   = (const float*)d_in[2];
  const float* ts        = (const float*)d_in[4];
  const float* ada_snorm = (const float*)d_in[7];
  const float* ada_scale_w = (const float*)d_in[8];
  const float* ada_scale_b = (const float*)d_in[9];
  const float* ada_shift_w = (const float*)d_in[10];
  const float* pb_q_w = (const float*)d_in[11];
  const float* pb_q_b = (const float*)d_in[12];
  const float* pb_k_w = (const float*)d_in[13];
  const float* pb_v_w = (const float*)d_in[14];
  const float* pb_g_w = (const float*)d_in[15];
  const float* pb_o_w = (const float*)d_in[16];
  const float* op_w = (const float*)d_in[17];
  const float* op_b = (const float*)d_in[18];
  const float* tr_snorm = (const float*)d_in[19];
  const float* tr_scale_w = (const float*)d_in[20];
  const float* tr_scale_b = (const float*)d_in[21];
  const float* tr_shift_w = (const float*)d_in[22];
  const float* tr_gate_w = (const float*)d_in[23];
  const float* tr_ab_w = (const float*)d_in[24];
  const float* tr_ba_w = (const float*)d_in[25];
  const float* tr_out_w = (const float*)d_in[26];
  const float* tr_out_b = (const float*)d_in[27];
  const float* tmp_ln_w = (const float*)d_in[28];
  const float* tmp_ln_b = (const float*)d_in[29];
  const float* tmp_q_w = (const float*)d_in[30];
  const float* tmp_q_b = (const float*)d_in[31];
  const float* tmp_k_w = (const float*)d_in[32];
  const float* tmp_v_w = (const float*)d_in[33];
  const float* tmp_decay = (const float*)d_in[34];
  const float* tmp_o_w = (const float*)d_in[35];

  char* ws = (char*)d_ws;
  short* W16 = (short*)ws;
  short* WADA1 = (short*)(ws + OFF_WADA1);
  short* WQKVG = (short*)(ws + OFF_WQKVG);
  short* WO = (short*)(ws + OFF_WO);
  short* WGATES = (short*)(ws + OFF_WGATES);
  short* WTMPQKV = (short*)(ws + OFF_WTMPQKV);
  short* WTMPO = (short*)(ws + OFF_WTMPO);
  short* WADA2 = (short*)(ws + OFF_WADA2);
  short* WTRANS = (short*)(ws + OFF_WTRANS);
  short* WBA = (short*)(ws + OFF_WBA);
  float* BIASB = (float*)(ws + OFF_BIAS);
  short* ZT = (short*)(ws + OFF_ZT);
  short* AN1 = (short*)(ws + OFF_AN1);
  short* SN1 = (short*)(ws + OFF_SN1);
  short* SN2 = (short*)(ws + OFF_SN2);
  short* SBF = (short*)(ws + OFF_SBF);
  short* CADA = (short*)(ws + OFF_CADA);
  short* QKVG = (short*)(ws + OFF_QKVG);
  short* GATES = (short*)(ws + OFF_GATES);
  short* OGO = (short*)(ws + OFF_OGO);
  float* A1F = (float*)(ws + OFF_A1);
  float* OUTF = (float*)d_out;

  // 1: all prep + ln_quad in one flat dispatch (5623 blocks, zero idle)
  prep_all<<<dim3(PREP_NBLK, 1, 1), 256, 0, stream>>>(
      ada_scale_w, ada_shift_w, pb_q_w, pb_k_w, pb_v_w, pb_g_w, pb_o_w,
      op_w, tr_out_w, tr_scale_w, tr_shift_w, tr_gate_w, tr_ab_w, tr_ba_w,
      tmp_q_w, tmp_k_w, tmp_v_w, tmp_o_w, W16,
      bias_in, ada_scale_b, pb_q_b, op_b, tr_out_b, tmp_q_b, tr_scale_b,
      BIASB, ZT,
      a_in, s_in, ada_snorm, tr_snorm, AN1, SN1, SN2, SBF);
  // 2: gates GEMM + AdaLN#1 dual fused (independent)
  gemm_pair<<<dim3(12, 64, 2), 512, 0, stream>>>(
      SBF, WGATES, BIASB + 4608, GATES, SN1, WADA1, BIASB + 0, AN1, SBF);
  // 3: qkvg
  gemm_bt<0><<<dim3(24, 64), 512, 0, stream>>>(SBF, WQKVG, BIASB + 1536, QKVG,
                                               nullptr, nullptr, 768, 768, 3072, 0);
  // 4: spatial attention (writes sigmoid(g)*o)
  attn_spatial<<<dim3(4, 12, 32), 256, 0, stream>>>(QKVG, ZT, OGO);
  // 5: a1 = a + gate_op * (go @ o_w)
  gemm_bt<3><<<dim3(6, 64), 512, 0, stream>>>(OGO, WO, nullptr, A1F, a_in, GATES,
                                              768, 768, 768, 1536);
  // 6: h = LN(a1)*w+b
  ln_affine<<<2048, 256, 0, stream>>>(A1F, tmp_ln_w, tmp_ln_b, AN1);
  // 7: temporal qkv
  gemm_bt<0><<<dim3(18, 64), 512, 0, stream>>>(AN1, WTMPQKV, BIASB + 6144, QKVG,
                                               nullptr, nullptr, 768, 768, 2304, 0);
  // 8: temporal attention
  attn_temporal<<<512, 256, 0, stream>>>(QKVG, ts, tmp_decay, OGO);
  // 9: a2 = a1 + tattn @ tmp_o_w   (in place)
  gemm_bt<2><<<dim3(6, 64), 512, 0, stream>>>(OGO, WTMPO, nullptr, A1F, A1F, nullptr,
                                              768, 768, 768, 0);
  // 10: an2 = LN(a2)
  ln_affine<<<2048, 256, 0, stream>>>(A1F, nullptr, nullptr, SN1);
  // 11: AdaLN #2 fused -> b2 in SBF
  gemm_dual<0><<<dim3(12, 64), 512, 0, stream>>>(SN2, WADA2, 768, BIASB + 8448, SN1,
                                                 SBF, 768);
  // 12: transition fused SwiGLU: hid = silu(b2@gate)*(b2@ab) -> CADA
  gemm_dual<1><<<dim3(24, 64), 512, 0, stream>>>(SBF, WTRANS, 1536, nullptr, nullptr,
                                                 CADA, 1536);
  // 13: out = a2 + gate_tr * (hid @ ba_w)
  gemm_bt<3><<<dim3(6, 64), 512, 0, stream>>>(CADA, WBA, nullptr, OUTF, A1F,
                                              GATES + 768, 1536, 1536, 768, 1536);
}

// Round 9
// 560.952 us; speedup vs baseline: 1.0935x; 1.0362x over previous
//
#include <hip/hip_runtime.h>

// ---------------------------------------------------------------------------
// Types / helpers
// ---------------------------------------------------------------------------
typedef short s16x8 __attribute__((ext_vector_type(8)));
typedef short s16x4 __attribute__((ext_vector_type(4)));
typedef float f32x4 __attribute__((ext_vector_type(4)));
typedef __bf16 bf16x8 __attribute__((ext_vector_type(8)));

__device__ __forceinline__ float bf2f(short u) {
  union { unsigned int i; float f; } c;
  c.i = ((unsigned int)(unsigned short)u) << 16;
  return c.f;
}
__device__ __forceinline__ short f2bf(float f) {
  union { float f; unsigned int i; } c; c.f = f;
  unsigned int r = c.i + 0x7FFFu + ((c.i >> 16) & 1u);  // RNE
  return (short)(r >> 16);
}
__device__ __forceinline__ float sigmoidf_(float x) { return 1.f / (1.f + __expf(-x)); }

template <typename T>
__device__ __forceinline__ auto mfma_sel(T a, T b, f32x4 c, int)
    -> decltype(__builtin_amdgcn_mfma_f32_16x16x32_bf16(a, b, c, 0, 0, 0)) {
  return __builtin_amdgcn_mfma_f32_16x16x32_bf16(a, b, c, 0, 0, 0);
}
template <typename T>
__device__ __forceinline__ f32x4 mfma_sel(T a, T b, f32x4 c, long) {
  return __builtin_amdgcn_mfma_f32_16x16x32_bf16(
      __builtin_bit_cast(bf16x8, a), __builtin_bit_cast(bf16x8, b), c, 0, 0, 0);
}
__device__ __forceinline__ f32x4 MFMA16(s16x8 a, s16x8 b, f32x4 c) {
  return mfma_sel(a, b, c, 0);
}

__device__ __forceinline__ void gl2lds16(const void* g, void* l) {
  __builtin_amdgcn_global_load_lds(
      (const __attribute__((address_space(1))) unsigned int*)g,
      (__attribute__((address_space(3))) unsigned int*)l, 16, 0, 0);
}

// Counted-vmcnt pipeline (T4). Per K-tile each thread issues 4 loads in 2
// units of 2. At a tile boundary: outstanding = 4 (current tile) + 2 (next
// tile's unitA) -> vmcnt(2) == current tile fully landed.
#define WAIT_VM2()  asm volatile("s_waitcnt vmcnt(2)" ::: "memory")
#define WAIT_VM0()  asm volatile("s_waitcnt vmcnt(0)" ::: "memory")
#define BAR()       __builtin_amdgcn_s_barrier()
#define PRIO1()     __builtin_amdgcn_s_setprio(1)
#define PRIO0()     __builtin_amdgcn_s_setprio(0)

// Bijective XCD-chunked swizzle (m204).
__device__ __forceinline__ int xcd_swz(int id, int nwg) {
  int q = nwg >> 3, r = nwg & 7;
  int xcd = id & 7, idx = id >> 3;
  return (xcd < r ? xcd * (q + 1) : r * (q + 1) + (xcd - r) * q) + idx;
}

// Superblocks of 8 m-rows, m fastest (B-panel L2-hot). gridDim.y == 64.
__device__ __forceinline__ void tile_mn(int nid, int gx, int* mt, int* nt) {
  int sb = nid / (gx << 3);
  int rem = nid - sb * (gx << 3);
  *mt = (sb << 3) + (rem & 7);
  *nt = rem >> 3;
}

// ---------------------------------------------------------------------------
// Workspace layout (byte offsets)
// ---------------------------------------------------------------------------
#define OFF_WADA1    0u
#define OFF_WQKVG    2359296u
#define OFF_WO       7077888u
#define OFF_WGATES   8257536u
#define OFF_WTMPQKV  10616832u
#define OFF_WTMPO    14155776u
#define OFF_WADA2    15335424u
#define OFF_WTRANS   17694720u
#define OFF_WBA      22413312u
#define OFF_BIAS     24772608u
#define OFF_ZT       24812544u
#define OFF_AN1      31104000u
#define OFF_SN1      43686912u
#define OFF_SN2      56269824u
#define OFF_SBF      68852736u
#define OFF_CADA     81435648u
#define OFF_QKVG     106601472u
#define OFF_GATES    156933120u
#define OFF_OGO      182098944u
#define OFF_A1       194681856u

// ---------------------------------------------------------------------------
// Mega prep kernel — flat 1-D grid, zero idle blocks:
//   [0, 1512)    : 18 weight transposes, 128(k)x64(n) tiles -> dst rows are
//                  256 B contiguous (s16x8 stores, full HBM lines)
//   [1512, 2024) : zt transpose, LDS-staged so stores are 512 B contiguous
//   [2024, 2063) : bias assembly
//   [2063, 4111) : ln_quad, 4 rows/block
// ---------------------------------------------------------------------------
#define PREP_NBLK 4111

__global__ __launch_bounds__(256) void prep_all(
    const float* p0, const float* p1, const float* p2, const float* p3,
    const float* p4, const float* p5, const float* p6, const float* p7,
    const float* p8, const float* p9, const float* p10, const float* p11,
    const float* p12, const float* p13, const float* p14, const float* p15,
    const float* p16, const float* p17, short* wsb,
    const float* __restrict__ zsrc, const float* __restrict__ ada_scale_b,
    const float* __restrict__ pb_q_b, const float* __restrict__ op_b,
    const float* __restrict__ tr_out_b, const float* __restrict__ tmp_q_b,
    const float* __restrict__ tr_scale_b,
    float* __restrict__ biasbuf, short* __restrict__ zt,
    const float* __restrict__ a_in, const float* __restrict__ s_in,
    const float* __restrict__ lnw1, const float* __restrict__ lnw2,
    short* __restrict__ an1, short* __restrict__ sn1, short* __restrict__ sn2,
    short* __restrict__ sbf) {
  __shared__ __align__(16) char shmem[33024];
  const int tid = threadIdx.x;
  const int bid = blockIdx.x;
  struct E { int K, N, dst; };
  const E tab[18] = {
      {768, 768, 0},        {768, 768, 589824},
      {768, 768, 1179648},  {768, 768, 1769472},
      {768, 768, 2359296},  {768, 768, 2949120},
      {768, 768, 3538944},
      {768, 768, 4128768},  {768, 768, 4718592},
      {768, 768, 7667712},  {768, 768, 8257536},
      {768, 1536, 8847360}, {768, 1536, 10027008},
      {1536, 768, 11206656},
      {768, 768, 5308416},  {768, 768, 5898240}, {768, 768, 6488064},
      {768, 768, 7077888}};
  if (bid < 1512) {
    // ---- weight transpose: src [K][N] fp32 -> dst [N][K] bf16.
    // 128(k) x 64(n) tile: reads 256 B/row, writes 256 B/row (full lines).
    int zidx = 0, base = 0;
    for (;;) {
      int tiles = (tab[zidx].K >> 7) * (tab[zidx].N >> 6);
      if (bid < base + tiles) break;
      base += tiles; ++zidx;
    }
    const int K = tab[zidx].K, N = tab[zidx].N;
    const int ntx = N >> 6;
    const int local = bid - base;
    const int n0 = (local % ntx) << 6;
    const int k0 = (local / ntx) << 7;
    const float* src;
    switch (zidx) {
      case 0: src = p0; break;  case 1: src = p1; break;
      case 2: src = p2; break;  case 3: src = p3; break;
      case 4: src = p4; break;  case 5: src = p5; break;
      case 6: src = p6; break;  case 7: src = p7; break;
      case 8: src = p8; break;  case 9: src = p9; break;
      case 10: src = p10; break; case 11: src = p11; break;
      case 12: src = p12; break; case 13: src = p13; break;
      case 14: src = p14; break; case 15: src = p15; break;
      case 16: src = p16; break; default: src = p17; break;
    }
    short* dst = wsb + tab[zidx].dst;
    float (*t)[129] = (float(*)[129])shmem;  // [64 n][129 k-pad]
#pragma unroll
    for (int j = 0; j < 8; j++) {
      int idx = (j << 8) + tid;
      int kr = idx >> 4, nc = (idx & 15) << 2;
      f32x4 v = *(const f32x4*)(src + (long)(k0 + kr) * N + n0 + nc);
      t[nc][kr] = v[0]; t[nc + 1][kr] = v[1];
      t[nc + 2][kr] = v[2]; t[nc + 3][kr] = v[3];
    }
    __syncthreads();
#pragma unroll
    for (int j = 0; j < 4; j++) {
      int idx = (j << 8) + tid;
      int nr = idx >> 4, kc = (idx & 15) << 3;
      s16x8 o;
#pragma unroll
      for (int e = 0; e < 8; e++) o[e] = f2bf(t[nr][kc + e]);
      *(s16x8*)(dst + (long)(n0 + nr) * K + k0 + kc) = o;
    }
  } else if (bid < 2024) {
    // ---- zt transpose (512 blocks): [kk=256][h=12] -> [h][kk], LDS-staged
    // so each store is s16x8 x 32 lanes = 512 B contiguous.
    const int bid2 = bid - 1512;
    const int b = bid2 >> 8, qq = bid2 & 255;
    short* zl = (short*)shmem;  // [12][264]
    const float* src = zsrc + (long)bid2 * 3072 + tid * 12;
    f32x4 v0 = *(const f32x4*)(src);
    f32x4 v1 = *(const f32x4*)(src + 4);
    f32x4 v2 = *(const f32x4*)(src + 8);
    float vals[12] = {v0[0], v0[1], v0[2], v0[3], v1[0], v1[1],
                      v1[2], v1[3], v2[0], v2[1], v2[2], v2[3]};
#pragma unroll
    for (int h = 0; h < 12; h++) zl[h * 264 + tid] = f2bf(vals[h]);
    __syncthreads();
#pragma unroll
    for (int it = 0; it < 2; it++) {
      int u = (it << 8) + tid;
      if (u < 384) {
        int h = u >> 5, kk = (u & 31) << 3;
        s16x8 o;
#pragma unroll
        for (int e = 0; e < 8; e++) o[e] = zl[h * 264 + kk + e];
        *(s16x8*)(zt + (((long)(b * 12 + h) * 256 + qq) << 8) + kk) = o;
      }
    }
  } else if (bid < 2063) {
    // ---- bias assembly (39 blocks, 9984 floats)
    int j = (bid - 2024) * 256 + tid;
    if (j < 9984) {
      float v;
      if (j < 1536) v = (j < 768) ? ada_scale_b[j] : 0.f;
      else if (j < 4608) { int jj = j - 1536; v = (jj < 768) ? pb_q_b[jj] : 0.f; }
      else if (j < 6144) { int jj = j - 4608; v = (jj < 768) ? op_b[jj] : tr_out_b[jj - 768]; }
      else if (j < 8448) { int jj = j - 6144; v = (jj < 768) ? tmp_q_b[jj] : 0.f; }
      else { int jj = j - 8448; v = (jj < 768) ? tr_scale_b[jj] : 0.f; }
      biasbuf[j] = v;
    }
  } else {
    // ---- ln_quad (2048 blocks, 4 rows each: wave-per-row)
    const int bid3 = bid - 2063;
    const int wave = tid >> 6, lane = tid & 63;
    const int row = (bid3 << 2) + wave;
    const float* ar = a_in + (long)row * 768;
    const float* sr = s_in + (long)row * 768;
    f32x4 av[3], sv[3];
    float s0 = 0, s1 = 0, s2 = 0, s3 = 0;
#pragma unroll
    for (int k = 0; k < 3; k++) {
      int col = (lane << 2) + (k << 8);
      av[k] = *(const f32x4*)(ar + col);
      sv[k] = *(const f32x4*)(sr + col);
#pragma unroll
      for (int e = 0; e < 4; e++) {
        s0 += av[k][e]; s1 += av[k][e] * av[k][e];
        s2 += sv[k][e]; s3 += sv[k][e] * sv[k][e];
      }
    }
#pragma unroll
    for (int o = 32; o; o >>= 1) {
      s0 += __shfl_xor(s0, o, 64); s1 += __shfl_xor(s1, o, 64);
      s2 += __shfl_xor(s2, o, 64); s3 += __shfl_xor(s3, o, 64);
    }
    const float inv768 = 1.f / 768.f;
    float ma = s0 * inv768, va = s1 * inv768 - ma * ma;
    float ia = rsqrtf(va + 1e-5f);
    float ms = s2 * inv768, vs = s3 * inv768 - ms * ms;
    float is_ = rsqrtf(vs + 1e-5f);
#pragma unroll
    for (int k = 0; k < 3; k++) {
      int col = (lane << 2) + (k << 8);
      long o = (long)row * 768 + col;
      s16x4 o1, o2, o3, o4;
#pragma unroll
      for (int e = 0; e < 4; e++) {
        o1[e] = f2bf((av[k][e] - ma) * ia);
        float sn = (sv[k][e] - ms) * is_;
        o2[e] = f2bf(sn * lnw1[col + e]);
        o3[e] = f2bf(sn * lnw2[col + e]);
        o4[e] = f2bf(sv[k][e]);
      }
      *(s16x4*)(an1 + o) = o1;
      *(s16x4*)(sn1 + o) = o2;
      *(s16x4*)(sn2 + o) = o3;
      *(s16x4*)(sbf + o) = o4;
    }
  }
}

// ---------------------------------------------------------------------------
// ln_affine (unchanged)
// ---------------------------------------------------------------------------
__global__ __launch_bounds__(256) void ln_affine(
    const float* __restrict__ in, const float* __restrict__ w,
    const float* __restrict__ b, short* __restrict__ out) {
  const int wave = threadIdx.x >> 6, lane = threadIdx.x & 63;
  const int row = (blockIdx.x << 2) + wave;
  const float* xr = in + (long)row * 768;
  f32x4 xv[3];
  float s0 = 0, s1 = 0;
#pragma unroll
  for (int k = 0; k < 3; k++) {
    int col = (lane << 2) + (k << 8);
    xv[k] = *(const f32x4*)(xr + col);
#pragma unroll
    for (int e = 0; e < 4; e++) { s0 += xv[k][e]; s1 += xv[k][e] * xv[k][e]; }
  }
#pragma unroll
  for (int o = 32; o; o >>= 1) { s0 += __shfl_xor(s0, o, 64); s1 += __shfl_xor(s1, o, 64); }
  const float inv768 = 1.f / 768.f;
  float m = s0 * inv768, v = s1 * inv768 - m * m;
  float inv = rsqrtf(v + 1e-5f);
#pragma unroll
  for (int k = 0; k < 3; k++) {
    int col = (lane << 2) + (k << 8);
    s16x4 p;
#pragma unroll
    for (int e = 0; e < 4; e++) {
      float y = (xv[k][e] - m) * inv;
      if (w) y = y * w[col + e] + b[col + e];
      p[e] = f2bf(y);
    }
    *(s16x4*)(out + (long)row * 768 + col) = p;
  }
}

// ---------------------------------------------------------------------------
// GEMM engine v3 — 128(m)x128(n) tile, 512 threads (8 waves, 2m x 4n),
// 64 KB double-buffered LDS, phase-split pipeline with counted vmcnt.
// ntoff: n-tile offset (for z-sliced merged dispatches).
// EP: 0 bf16(+bias), 1 bf16 sigmoid(+bias), 2 f32 res+acc, 3 f32 res+gate*acc
// ---------------------------------------------------------------------------
template <int EP>
__device__ __forceinline__ void dev_gemm_bt(
    short* lds,
    const short* __restrict__ A, const short* __restrict__ W,
    const float* __restrict__ bias, void* __restrict__ Cout,
    const float* __restrict__ res, const short* __restrict__ gate,
    int K, int ldA, int ldC, int gld, int ntoff) {
  const int tid = threadIdx.x;           // 0..511
  const int wave = tid >> 6;             // 0..7
  const int lane = tid & 63;
  const int gx = gridDim.x;
  const int nid = xcd_swz(blockIdx.y * gx + blockIdx.x, gx * gridDim.y);
  int mt_, nt_;
  tile_mn(nid, gx, &mt_, &nt_);
  const int m0 = mt_ << 7;
  const int n0 = (nt_ + ntoff) << 7;
  const int wm = (wave & 1) << 6;        // 0,64
  const int wn = (wave >> 1) << 5;       // 0,32,64,96
  const int q = lane >> 4, r = lane & 15;
  f32x4 acc[4][2];
#pragma unroll
  for (int i = 0; i < 4; i++)
#pragma unroll
    for (int j = 0; j < 2; j++) acc[i][j] = (f32x4){0.f, 0.f, 0.f, 0.f};

  const short* pA[2];
  const short* pB[2];
#pragma unroll
  for (int j = 0; j < 2; j++) {
    int c = (j << 9) + tid;
    int m = c >> 3, kc = (c & 7) ^ (m & 7);
    pA[j] = A + (long)(m0 + m) * ldA + (kc << 3);
    pB[j] = W + (long)(n0 + m) * K + (kc << 3);
  }
  const int lA0 = (wave << 9);
  const int lA1 = (1 << 12) + (wave << 9);
  const int lB0 = 8192 + (wave << 9);
  const int lB1 = 8192 + (1 << 12) + (wave << 9);

  int offA[4][2], offB[2][2];
#pragma unroll
  for (int p = 0; p < 4; p++)
#pragma unroll
    for (int ks = 0; ks < 2; ks++) {
      int row = wm + (p << 4) + r;
      offA[p][ks] = ((row << 3) + (((ks << 2) + q) ^ (row & 7))) << 3;
    }
#pragma unroll
  for (int ks = 0; ks < 2; ks++)
#pragma unroll
    for (int nt = 0; nt < 2; nt++) {
      int row = wn + (nt << 4) + r;
      offB[ks][nt] = 8192 + (((row << 3) + (((ks << 2) + q) ^ (row & 7))) << 3);
    }

  auto unitA = [&](short* buf, int ko) {
    gl2lds16(pA[0] + ko, buf + lA0);
    gl2lds16(pA[1] + ko, buf + lA1);
  };
  auto unitB = [&](short* buf, int ko) {
    gl2lds16(pB[0] + ko, buf + lB0);
    gl2lds16(pB[1] + ko, buf + lB1);
  };

  s16x8 bv[2][2];
  auto loadbv = [&](const short* buf) {
#pragma unroll
    for (int ks = 0; ks < 2; ks++)
#pragma unroll
      for (int nt = 0; nt < 2; nt++)
        bv[ks][nt] = *(const s16x8*)(buf + offB[ks][nt]);
  };
  auto phase = [&](const short* buf, int p) {
    s16x8 a0 = *(const s16x8*)(buf + offA[p][0]);
    s16x8 a1 = *(const s16x8*)(buf + offA[p][1]);
    PRIO1();
#pragma unroll
    for (int nt = 0; nt < 2; nt++) {
      acc[p][nt] = MFMA16(bv[0][nt], a0, acc[p][nt]);
      acc[p][nt] = MFMA16(bv[1][nt], a1, acc[p][nt]);
    }
    PRIO0();
  };

  auto TILE = [&](const short* cur, short* nxt, int ko) {
    unitA(nxt, ko);
    WAIT_VM2(); BAR();
    loadbv(cur);
    phase(cur, 0);
    unitB(nxt, ko);
    phase(cur, 1);
    phase(cur, 2);
    phase(cur, 3);
    BAR();
  };

  short* b0 = lds;
  short* b1 = lds + 16384;
  const int NT = K >> 6;  // even (12 or 24)
  unitA(b0, 0); unitB(b0, 0);
  int t = 0;
  for (; t + 2 < NT; t += 2) {
    TILE(b0, b1, (t + 1) << 6);
    TILE(b1, b0, (t + 2) << 6);
  }
  TILE(b0, b1, (t + 1) << 6);  // computes tile NT-2, stages NT-1
  WAIT_VM0(); BAR();
  loadbv(b1);
  phase(b1, 0); phase(b1, 1); phase(b1, 2); phase(b1, 3);

#pragma unroll
  for (int mt = 0; mt < 4; mt++) {
    const int gm = m0 + wm + (mt << 4) + r;
#pragma unroll
    for (int nt = 0; nt < 2; nt++) {
      const int gnb = n0 + wn + (nt << 4) + (q << 2);
      f32x4 v = acc[mt][nt];
      if (bias) {
        f32x4 b4 = *(const f32x4*)(bias + gnb);
        v += b4;
      }
      long o = (long)gm * ldC + gnb;
      if (EP == 0) {
        s16x4 p;
#pragma unroll
        for (int e = 0; e < 4; e++) p[e] = f2bf(v[e]);
        *(s16x4*)((short*)Cout + o) = p;
      } else if (EP == 1) {
        s16x4 p;
#pragma unroll
        for (int e = 0; e < 4; e++) p[e] = f2bf(sigmoidf_(v[e]));
        *(s16x4*)((short*)Cout + o) = p;
      } else if (EP == 2) {
        f32x4 r4 = *(const f32x4*)(res + o);
        *(f32x4*)((float*)Cout + o) = r4 + v;
      } else {
        f32x4 r4 = *(const f32x4*)(res + o);
        s16x4 g4 = *(const s16x4*)(gate + (long)gm * gld + gnb);
        f32x4 out;
#pragma unroll
        for (int e = 0; e < 4; e++) out[e] = r4[e] + bf2f(g4[e]) * v[e];
        *(f32x4*)((float*)Cout + o) = out;
      }
    }
  }
}

// Dual GEMM v3 — 128(m) x (64|64)(n) halves (unchanged from r8).
// MODE 0 (adaln): out = bf16( sigmoid(c1+bias)*an + c2 ); MODE 1: silu(c1)*c2
template <int MODE>
__device__ __forceinline__ void dev_gemm_dual(
    short* lds,
    const short* __restrict__ A, const short* __restrict__ W, int woff2,
    const float* __restrict__ bias, const short* __restrict__ an,
    short* __restrict__ out, int ldO) {
  const int tid = threadIdx.x;
  const int wave = tid >> 6, lane = tid & 63;
  const int gx = gridDim.x;
  const int nid = xcd_swz(blockIdx.y * gx + blockIdx.x, gx * gridDim.y);
  int mt_, nt_;
  tile_mn(nid, gx, &mt_, &nt_);
  const int m0 = mt_ << 7;
  const int n0 = nt_ << 6;               // 64-col tiles per half
  const int wm = (wave & 1) << 6;        // 0,64
  const int wn = (wave >> 1) << 4;       // 0,16,32,48
  const int q = lane >> 4, r = lane & 15;
  f32x4 acc1[4], acc2[4];
#pragma unroll
  for (int i = 0; i < 4; i++) {
    acc1[i] = (f32x4){0.f, 0.f, 0.f, 0.f};
    acc2[i] = (f32x4){0.f, 0.f, 0.f, 0.f};
  }

  const short* pA[2];
  const short* pB1;
  const short* pB2;
#pragma unroll
  for (int j = 0; j < 2; j++) {
    int c = (j << 9) + tid;
    int m = c >> 3, kc = (c & 7) ^ (m & 7);
    pA[j] = A + (long)(m0 + m) * 768 + (kc << 3);
  }
  {
    int m = tid >> 3, kc = (tid & 7) ^ (m & 7);
    pB1 = W + (long)(n0 + m) * 768 + (kc << 3);
    pB2 = W + (long)(woff2 + n0 + m) * 768 + (kc << 3);
  }
  const int lA0 = (wave << 9);
  const int lA1 = (1 << 12) + (wave << 9);
  const int lB1o = 8192 + (wave << 9);
  const int lB2o = 12288 + (wave << 9);

  int offA[4][2], offB[2];
#pragma unroll
  for (int p = 0; p < 4; p++)
#pragma unroll
    for (int ks = 0; ks < 2; ks++) {
      int row = wm + (p << 4) + r;
      offA[p][ks] = ((row << 3) + (((ks << 2) + q) ^ (row & 7))) << 3;
    }
#pragma unroll
  for (int ks = 0; ks < 2; ks++) {
    int row = wn + r;
    offB[ks] = ((row << 3) + (((ks << 2) + q) ^ (row & 7))) << 3;
  }

  auto unitA = [&](short* buf, int ko) {
    gl2lds16(pA[0] + ko, buf + lA0);
    gl2lds16(pA[1] + ko, buf + lA1);
  };
  auto unitB = [&](short* buf, int ko) {
    gl2lds16(pB1 + ko, buf + lB1o);
    gl2lds16(pB2 + ko, buf + lB2o);
  };

  s16x8 b1v[2], b2v[2];
  auto loadbv = [&](const short* buf) {
#pragma unroll
    for (int ks = 0; ks < 2; ks++) {
      b1v[ks] = *(const s16x8*)(buf + 8192 + offB[ks]);
      b2v[ks] = *(const s16x8*)(buf + 12288 + offB[ks]);
    }
  };
  auto phase = [&](const short* buf, int p) {
    s16x8 a0 = *(const s16x8*)(buf + offA[p][0]);
    s16x8 a1 = *(const s16x8*)(buf + offA[p][1]);
    PRIO1();
    acc1[p] = MFMA16(b1v[0], a0, acc1[p]);
    acc1[p] = MFMA16(b1v[1], a1, acc1[p]);
    acc2[p] = MFMA16(b2v[0], a0, acc2[p]);
    acc2[p] = MFMA16(b2v[1], a1, acc2[p]);
    PRIO0();
  };
  auto TILE = [&](const short* cur, short* nxt, int ko) {
    unitA(nxt, ko);
    WAIT_VM2(); BAR();
    loadbv(cur);
    phase(cur, 0);
    unitB(nxt, ko);
    phase(cur, 1);
    phase(cur, 2);
    phase(cur, 3);
    BAR();
  };

  short* bb0 = lds;
  short* bb1 = lds + 16384;
  const int NT = 12;  // K = 768
  unitA(bb0, 0); unitB(bb0, 0);
  int t = 0;
  for (; t + 2 < NT; t += 2) {
    TILE(bb0, bb1, (t + 1) << 6);
    TILE(bb1, bb0, (t + 2) << 6);
  }
  TILE(bb0, bb1, (t + 1) << 6);
  WAIT_VM0(); BAR();
  loadbv(bb1);
  phase(bb1, 0); phase(bb1, 1); phase(bb1, 2); phase(bb1, 3);

#pragma unroll
  for (int mt = 0; mt < 4; mt++) {
    const int gm = m0 + wm + (mt << 4) + r;
    const int gnb = n0 + wn + (q << 2);
    s16x4 p;
    if (MODE == 0) {
      f32x4 b4 = *(const f32x4*)(bias + gnb);
      s16x4 an4 = *(const s16x4*)(an + (long)gm * 768 + gnb);
#pragma unroll
      for (int e = 0; e < 4; e++)
        p[e] = f2bf(sigmoidf_(acc1[mt][e] + b4[e]) * bf2f(an4[e]) +
                    acc2[mt][e]);
    } else {
#pragma unroll
      for (int e = 0; e < 4; e++) {
        float x = acc1[mt][e];
        p[e] = f2bf(x * sigmoidf_(x) * acc2[mt][e]);
      }
    }
    *(s16x4*)(out + (long)gm * ldO + gnb) = p;
  }
}

template <int EP>
__global__ __launch_bounds__(512, 4) void gemm_bt(
    const short* __restrict__ A, const short* __restrict__ W,
    const float* __restrict__ bias, void* __restrict__ Cout,
    const float* __restrict__ res, const short* __restrict__ gate,
    int K, int ldA, int ldC, int gld) {
  __shared__ short lds[32768];
  dev_gemm_bt<EP>(lds, A, W, bias, Cout, res, gate, K, ldA, ldC, gld, 0);
}

template <int MODE>
__global__ __launch_bounds__(512, 4) void gemm_dual(
    const short* __restrict__ A, const short* __restrict__ W, int woff2,
    const float* __restrict__ bias, const short* __restrict__ an,
    short* __restrict__ out, int ldO) {
  __shared__ short lds[32768];
  dev_gemm_dual<MODE>(lds, A, W, woff2, bias, an, out, ldO);
}

// Merged head: z=0 gates GEMM (sigmoid), z=1 AdaLN#1 dual, z=2/3 qkvg halves.
// All three depend only on prep outputs -> one dispatch, 3072 blocks = 6 full
// CU rounds (vs two dispatches with tails + a stream boundary).
__global__ __launch_bounds__(512, 4) void gemm_head(
    const short* __restrict__ sbf, const short* __restrict__ wgates,
    const float* __restrict__ bias_g, short* __restrict__ gates,
    const short* __restrict__ sn1, const short* __restrict__ wada1,
    const float* __restrict__ bias_a, const short* __restrict__ an1,
    short* __restrict__ outb,
    const short* __restrict__ wqkvg, const float* __restrict__ bias_q,
    short* __restrict__ qkvg) {
  __shared__ short lds[32768];
  const int z = blockIdx.z;
  if (z == 0)
    dev_gemm_bt<1>(lds, sbf, wgates, bias_g, (void*)gates, nullptr, nullptr,
                   768, 768, 1536, 0, 0);
  else if (z == 1)
    dev_gemm_dual<0>(lds, sn1, wada1, 768, bias_a, an1, outb, 768);
  else
    dev_gemm_bt<0>(lds, sbf, wqkvg, bias_q, (void*)qkvg, nullptr, nullptr,
                   768, 768, 3072, 0, (z - 2) * 12);
}

// ---------------------------------------------------------------------------
// Spatial attention (unchanged)
// ---------------------------------------------------------------------------
__global__ __launch_bounds__(256) void attn_spatial(
    const short* __restrict__ qkvg, const short* __restrict__ zt, short* __restrict__ ogo) {
  __shared__ short sKP[256 * 64];
  __shared__ short sVt[64 * 256];
  const int tid = threadIdx.x;
  const int wave = tid >> 6, lane = tid & 63;
  const int qt = blockIdx.x, h = blockIdx.y, bt = blockIdx.z;
  const int b = bt >> 4;
  const int q0 = qt << 6;
  const long rowbase = (long)bt << 8;
  const int hoff = h << 6;

#pragma unroll
  for (int t = 0; t < 8; t++) {
    int c = (t << 8) + tid;
    int tok = c >> 3, kc = (c & 7) ^ (tok & 7);
    *(s16x8*)(sKP + (c << 3)) =
        *(const s16x8*)(qkvg + (rowbase + tok) * 3072 + 768 + hoff + (kc << 3));
  }
#pragma unroll
  for (int t = 0; t < 8; t++) {
    int u = (t << 8) + tid;
    int tok = u >> 3, dc = u & 7;
    s16x8 v8 = *(const s16x8*)(qkvg + (rowbase + tok) * 3072 + 1536 + hoff + (dc << 3));
#pragma unroll
    for (int e = 0; e < 8; e++) {
      int d = (dc << 3) + e;
      int ch = (tok >> 3) ^ (d & 7);
      sVt[((d << 5) + ch) * 8 + (tok & 7)] = v8[e];
    }
  }
  __syncthreads();

  const int q = lane >> 4, cc = lane & 15;
  f32x4 acc[16];
#pragma unroll
  for (int i = 0; i < 16; i++) acc[i] = (f32x4){0.f, 0.f, 0.f, 0.f};
  {
    const int arow = (wave << 4) + cc;
    const short* qrow = qkvg + (rowbase + q0 + arow) * 3072 + hoff;
#pragma unroll
    for (int ks = 0; ks < 2; ks++) {
      s16x8 av = *(const s16x8*)(qrow + (ks << 5) + (q << 3));
#pragma unroll
      for (int nt = 0; nt < 16; nt++) {
        int tok = (nt << 4) + cc;
        int chb = ((ks << 2) + q) ^ (tok & 7);
        s16x8 bv = *(const s16x8*)(sKP + ((tok << 3) + chb) * 8);
        acc[nt] = MFMA16(av, bv, acc[nt]);
      }
    }
  }
  const short* ztb = zt + (((long)(b * 12 + h) * 256 + q0 + (wave << 4)) << 8);
#pragma unroll
  for (int reg = 0; reg < 4; reg++) {
    int lr = (q << 2) + reg;
    float mx = -3.0e38f;
#pragma unroll
    for (int nt = 0; nt < 16; nt++) {
      float v = acc[nt][reg] * 0.125f + bf2f(ztb[lr * 256 + (nt << 4) + cc]);
      acc[nt][reg] = v;
      mx = fmaxf(mx, v);
    }
    mx = fmaxf(mx, __shfl_xor(mx, 1, 16));
    mx = fmaxf(mx, __shfl_xor(mx, 2, 16));
    mx = fmaxf(mx, __shfl_xor(mx, 4, 16));
    mx = fmaxf(mx, __shfl_xor(mx, 8, 16));
    float sum = 0.f;
#pragma unroll
    for (int nt = 0; nt < 16; nt++) {
      float e = __expf(acc[nt][reg] - mx);
      acc[nt][reg] = e; sum += e;
    }
    sum += __shfl_xor(sum, 1, 16);
    sum += __shfl_xor(sum, 2, 16);
    sum += __shfl_xor(sum, 4, 16);
    sum += __shfl_xor(sum, 8, 16);
    float inv = 1.f / sum;
#pragma unroll
    for (int nt = 0; nt < 16; nt++) acc[nt][reg] *= inv;
  }
  __syncthreads();
#pragma unroll
  for (int nt = 0; nt < 16; nt++) {
#pragma unroll
    for (int reg = 0; reg < 4; reg++) {
      int rP = (wave << 4) + (q << 2) + reg;
      int col = (nt << 4) + cc;
      int ch = (col >> 3) ^ (rP & 7);
      sKP[((rP << 5) + ch) * 8 + (col & 7)] = f2bf(acc[nt][reg]);
    }
  }
  __syncthreads();
  f32x4 oacc[4];
#pragma unroll
  for (int i = 0; i < 4; i++) oacc[i] = (f32x4){0.f, 0.f, 0.f, 0.f};
  const int prow = (wave << 4) + cc;
#pragma unroll
  for (int ksi = 0; ksi < 8; ksi++) {
    int cha = ((ksi << 2) + q) ^ (prow & 7);
    s16x8 pa = *(const s16x8*)(sKP + ((prow << 5) + cha) * 8);
#pragma unroll
    for (int dt = 0; dt < 4; dt++) {
      int d = (dt << 4) + cc;
      int chv = ((ksi << 2) + q) ^ (d & 7);
      s16x8 bv = *(const s16x8*)(sVt + ((d << 5) + chv) * 8);
      oacc[dt] = MFMA16(pa, bv, oacc[dt]);
    }
  }
#pragma unroll
  for (int dt = 0; dt < 4; dt++) {
#pragma unroll
    for (int reg = 0; reg < 4; reg++) {
      int rowt = q0 + (wave << 4) + (q << 2) + reg;
      int dcol = (dt << 4) + cc;
      long grow = rowbase + rowt;
      float gl = bf2f(qkvg[grow * 3072 + 2304 + hoff + dcol]);
      ogo[grow * 768 + hoff + dcol] = f2bf(oacc[dt][reg] * sigmoidf_(gl));
    }
  }
}

// ---------------------------------------------------------------------------
// Temporal attention (unchanged)
// ---------------------------------------------------------------------------
__global__ __launch_bounds__(256) void attn_temporal(
    const short* __restrict__ qkvt, const float* __restrict__ ts,
    const float* __restrict__ decay_raw, short* __restrict__ out) {
  __shared__ short sKV[16 * 1544];
  const int bn = blockIdx.x;
  const int b = bn >> 8, n = bn & 255;
  const int tid = threadIdx.x;
#pragma unroll
  for (int t = 0; t < 12; t++) {
    int u = t * 256 + tid;
    int row = u / 192, cc = u % 192;
    *(s16x8*)(sKV + row * 1544 + cc * 8) =
        *(const s16x8*)(qkvt + ((long)(b * 16 + row) * 256 + n) * 2304 + 768 + cc * 8);
  }
  __syncthreads();
  const int h = tid >> 4, tq = tid & 15;
  if (h < 12) {
    const int hoff = h << 6;
    float dec = log1pf(__expf(decay_raw[h]));
    float tsq = ts[b * 16 + tq];
    s16x8 qv[8];
    const short* qrow = qkvt + ((long)(b * 16 + tq) * 256 + n) * 2304 + hoff;
#pragma unroll
    for (int dc = 0; dc < 8; dc++) qv[dc] = *(const s16x8*)(qrow + dc * 8);
    float sc[16];
#pragma unroll
    for (int tk = 0; tk < 16; tk++) {
      float dot = 0.f;
#pragma unroll
      for (int dc = 0; dc < 8; dc++) {
        s16x8 kv = *(const s16x8*)(sKV + tk * 1544 + hoff + dc * 8);
#pragma unroll
        for (int e = 0; e < 8; e++) dot += bf2f(qv[dc][e]) * bf2f(kv[e]);
      }
      sc[tk] = dot * 0.125f - dec * fabsf(tsq - ts[b * 16 + tk]);
    }
    float mx = sc[0];
#pragma unroll
    for (int tk = 1; tk < 16; tk++) mx = fmaxf(mx, sc[tk]);
    float sum = 0.f;
#pragma unroll
    for (int tk = 0; tk < 16; tk++) { sc[tk] = __expf(sc[tk] - mx); sum += sc[tk]; }
    float inv = 1.f / sum;
    float oa[64];
#pragma unroll
    for (int d = 0; d < 64; d++) oa[d] = 0.f;
#pragma unroll
    for (int tk = 0; tk < 16; tk++) {
      float wgt = sc[tk] * inv;
#pragma unroll
      for (int dc = 0; dc < 8; dc++) {
        s16x8 vv = *(const s16x8*)(sKV + tk * 1544 + 768 + hoff + dc * 8);
#pragma unroll
        for (int e = 0; e < 8; e++) oa[dc * 8 + e] += wgt * bf2f(vv[e]);
      }
    }
    long orow = (long)(b * 16 + tq) * 256 + n;
#pragma unroll
    for (int dc = 0; dc < 8; dc++) {
      s16x8 o8;
#pragma unroll
      for (int e = 0; e < 8; e++) o8[e] = f2bf(oa[dc * 8 + e]);
      *(s16x8*)(out + orow * 768 + hoff + dc * 8) = o8;
    }
  }
}

// ---------------------------------------------------------------------------
// Host launcher
// ---------------------------------------------------------------------------
extern "C" void kernel_launch(void* const* d_in, const int* in_sizes, int n_in,
                              void* d_out, int out_size, void* d_ws, size_t ws_size,
                              hipStream_t stream) {
  (void)in_sizes; (void)n_in; (void)out_size; (void)ws_size;
  const float* a_in      = (const float*)d_in[0];
  const float* s_in      = (const float*)d_in[1];
  const float* bias_in   = (const float*)d_in[2];
  const float* ts        = (const float*)d_in[4];
  const float* ada_snorm = (const float*)d_in[7];
  const float* ada_scale_w = (const float*)d_in[8];
  const float* ada_scale_b = (const float*)d_in[9];
  const float* ada_shift_w = (const float*)d_in[10];
  const float* pb_q_w = (const float*)d_in[11];
  const float* pb_q_b = (const float*)d_in[12];
  const float* pb_k_w = (const float*)d_in[13];
  const float* pb_v_w = (const float*)d_in[14];
  const float* pb_g_w = (const float*)d_in[15];
  const float* pb_o_w = (const float*)d_in[16];
  const float* op_w = (const float*)d_in[17];
  const float* op_b = (const float*)d_in[18];
  const float* tr_snorm = (const float*)d_in[19];
  const float* tr_scale_w = (const float*)d_in[20];
  const float* tr_scale_b = (const float*)d_in[21];
  const float* tr_shift_w = (const float*)d_in[22];
  const float* tr_gate_w = (const float*)d_in[23];
  const float* tr_ab_w = (const float*)d_in[24];
  const float* tr_ba_w = (const float*)d_in[25];
  const float* tr_out_w = (const float*)d_in[26];
  const float* tr_out_b = (const float*)d_in[27];
  const float* tmp_ln_w = (const float*)d_in[28];
  const float* tmp_ln_b = (const float*)d_in[29];
  const float* tmp_q_w = (const float*)d_in[30];
  const float* tmp_q_b = (const float*)d_in[31];
  const float* tmp_k_w = (const float*)d_in[32];
  const float* tmp_v_w = (const float*)d_in[33];
  const float* tmp_decay = (const float*)d_in[34];
  const float* tmp_o_w = (const float*)d_in[35];

  char* ws = (char*)d_ws;
  short* W16 = (short*)ws;
  short* WADA1 = (short*)(ws + OFF_WADA1);
  short* WQKVG = (short*)(ws + OFF_WQKVG);
  short* WO = (short*)(ws + OFF_WO);
  short* WGATES = (short*)(ws + OFF_WGATES);
  short* WTMPQKV = (short*)(ws + OFF_WTMPQKV);
  short* WTMPO = (short*)(ws + OFF_WTMPO);
  short* WADA2 = (short*)(ws + OFF_WADA2);
  short* WTRANS = (short*)(ws + OFF_WTRANS);
  short* WBA = (short*)(ws + OFF_WBA);
  float* BIASB = (float*)(ws + OFF_BIAS);
  short* ZT = (short*)(ws + OFF_ZT);
  short* AN1 = (short*)(ws + OFF_AN1);
  short* SN1 = (short*)(ws + OFF_SN1);
  short* SN2 = (short*)(ws + OFF_SN2);
  short* SBF = (short*)(ws + OFF_SBF);
  short* CADA = (short*)(ws + OFF_CADA);
  short* QKVG = (short*)(ws + OFF_QKVG);
  short* GATES = (short*)(ws + OFF_GATES);
  short* OGO = (short*)(ws + OFF_OGO);
  float* A1F = (float*)(ws + OFF_A1);
  float* OUTF = (float*)d_out;

  // 1: all prep + ln_quad in one flat dispatch (4111 blocks, zero idle)
  prep_all<<<dim3(PREP_NBLK, 1, 1), 256, 0, stream>>>(
      ada_scale_w, ada_shift_w, pb_q_w, pb_k_w, pb_v_w, pb_g_w, pb_o_w,
      op_w, tr_out_w, tr_scale_w, tr_shift_w, tr_gate_w, tr_ab_w, tr_ba_w,
      tmp_q_w, tmp_k_w, tmp_v_w, tmp_o_w, W16,
      bias_in, ada_scale_b, pb_q_b, op_b, tr_out_b, tmp_q_b, tr_scale_b,
      BIASB, ZT,
      a_in, s_in, ada_snorm, tr_snorm, AN1, SN1, SN2, SBF);
  // 2: gates GEMM + AdaLN#1 dual + qkvg, all prep-dependent -> one dispatch
  gemm_head<<<dim3(12, 64, 4), 512, 0, stream>>>(
      SBF, WGATES, BIASB + 4608, GATES, SN1, WADA1, BIASB + 0, AN1, SBF,
      WQKVG, BIASB + 1536, QKVG);
  // 3: spatial attention (writes sigmoid(g)*o)
  attn_spatial<<<dim3(4, 12, 32), 256, 0, stream>>>(QKVG, ZT, OGO);
  // 4: a1 = a + gate_op * (go @ o_w)
  gemm_bt<3><<<dim3(6, 64), 512, 0, stream>>>(OGO, WO, nullptr, A1F, a_in, GATES,
                                              768, 768, 768, 1536);
  // 5: h = LN(a1)*w+b
  ln_affine<<<2048, 256, 0, stream>>>(A1F, tmp_ln_w, tmp_ln_b, AN1);
  // 6: temporal qkv
  gemm_bt<0><<<dim3(18, 64), 512, 0, stream>>>(AN1, WTMPQKV, BIASB + 6144, QKVG,
                                               nullptr, nullptr, 768, 768, 2304, 0);
  // 7: temporal attention
  attn_temporal<<<512, 256, 0, stream>>>(QKVG, ts, tmp_decay, OGO);
  // 8: a2 = a1 + tattn @ tmp_o_w   (in place)
  gemm_bt<2><<<dim3(6, 64), 512, 0, stream>>>(OGO, WTMPO, nullptr, A1F, A1F, nullptr,
                                              768, 768, 768, 0);
  // 9: an2 = LN(a2)
  ln_affine<<<2048, 256, 0, stream>>>(A1F, nullptr, nullptr, SN1);
  // 10: AdaLN #2 fused -> b2 in SBF
  gemm_dual<0><<<dim3(12, 64), 512, 0, stream>>>(SN2, WADA2, 768, BIASB + 8448, SN1,
                                                 SBF, 768);
  // 11: transition fused SwiGLU: hid = silu(b2@gate)*(b2@ab) -> CADA
  gemm_dual<1><<<dim3(24, 64), 512, 0, stream>>>(SBF, WTRANS, 1536, nullptr, nullptr,
                                                 CADA, 1536);
  // 12: out = a2 + gate_tr * (hid @ ba_w)
  gemm_bt<3><<<dim3(6, 64), 512, 0, stream>>>(CADA, WBA, nullptr, OUTF, A1F,
                                              GATES + 768, 1536, 1536, 768, 1536);
}